// Round 1
// baseline (2529.564 us; speedup 1.0000x reference)
//
#include <hip/hip_runtime.h>
#include <cstdint>
#include <cstddef>

// Problem constants (B=2, S=2048, D=1024, H=16, DH=64, DM=4096)
#define SEQ    2048
#define DMODEL 1024
#define NHEAD  16
#define DHEAD  64
#define DMLP   4096
#define ROWS   4096   // B*S

// ---------------------------------------------------------------- utilities
__device__ __forceinline__ float wave_reduce_sum(float v) {
#pragma unroll
  for (int off = 32; off; off >>= 1) v += __shfl_xor(v, off, 64);
  return v;
}
__device__ __forceinline__ float wave_reduce_max(float v) {
#pragma unroll
  for (int off = 32; off; off >>= 1) v = fmaxf(v, __shfl_xor(v, off, 64));
  return v;
}
__device__ __forceinline__ float gelu_new(float x) {
  // 0.5*x*(1+tanh(sqrt(2/pi)*(x+0.044715*x^3)))  (jax.nn.gelu approximate=True)
  const float c = 0.7978845608028654f;
  float inner = c * (x + 0.044715f * x * x * x);
  return 0.5f * x * (1.0f + tanhf(inner));
}

// ---------------------------------------------------------------- LayerNorm
// TransformerLens LN: center, scale by sqrt(mean(centered^2)+eps), affine.
// One block (256 threads) per row of 1024; each thread handles one float4.
__global__ __launch_bounds__(256)
void ln_kernel(const float* __restrict__ x, const float* __restrict__ w,
               const float* __restrict__ b, float* __restrict__ y) {
  __shared__ float sred[4];
  const int r = blockIdx.x;
  const int t = threadIdx.x;
  const int wid = t >> 6, lane = t & 63;
  const float4 v = ((const float4*)(x + (size_t)r * DMODEL))[t];

  float s = v.x + v.y + v.z + v.w;
  s = wave_reduce_sum(s);
  if (lane == 0) sred[wid] = s;
  __syncthreads();
  const float mean = (sred[0] + sred[1] + sred[2] + sred[3]) * (1.0f / DMODEL);
  __syncthreads();

  float4 c;
  c.x = v.x - mean; c.y = v.y - mean; c.z = v.z - mean; c.w = v.w - mean;
  float ss = c.x * c.x + c.y * c.y + c.z * c.z + c.w * c.w;
  ss = wave_reduce_sum(ss);
  if (lane == 0) sred[wid] = ss;
  __syncthreads();
  const float rs =
      rsqrtf((sred[0] + sred[1] + sred[2] + sred[3]) * (1.0f / DMODEL) + 1e-5f);

  const float4 wv = ((const float4*)w)[t];
  const float4 bv = ((const float4*)b)[t];
  float4 o;
  o.x = c.x * rs * wv.x + bv.x;
  o.y = c.y * rs * wv.y + bv.y;
  o.z = c.z * rs * wv.z + bv.z;
  o.w = c.w * rs * wv.w + bv.w;
  ((float4*)(y + (size_t)r * DMODEL))[t] = o;
}

// ---------------------------------------------------------------- GEMM
// C[M x 64*gridDim.y] = A[M x K] @ B + bias (+epilogue). 64x64 tile, BK=32,
// 256 threads, each thread 4x4. Per-block B panel: Bbase + blockIdx.y*bstride,
// accessed row-major with ldb (handles W_Q's [H,D,DH] head-blocked layout).
// EPI: 0 = store, 1 = gelu, 2 = +addend (residual), 3 = accumulate into C.
template <int EPI>
__global__ __launch_bounds__(256)
void gemm64(const float* __restrict__ A, int lda,
            const float* __restrict__ Bbase, long long bstride, int ldb,
            const float* __restrict__ bias, const float* __restrict__ addend,
            float* __restrict__ C, int ldc, int K) {
  __shared__ float As[32][68];  // transposed A tile: As[k][m], padded
  __shared__ float Bs[32][68];  // Bs[k][n], padded
  const int tid = threadIdx.x;
  const int tx = tid & 15, ty = tid >> 4;
  const int m0 = blockIdx.x * 64;
  const int n0 = blockIdx.y * 64;
  const float* Bp = Bbase + (long long)blockIdx.y * bstride;

  float acc[4][4] = {};

  for (int k0 = 0; k0 < K; k0 += 32) {
    __syncthreads();
#pragma unroll
    for (int it = 0; it < 2; ++it) {  // stage A 64x32 (transposed into LDS)
      int flat = it * 256 + tid;
      int row = flat >> 3, cc = (flat & 7) * 4;
      const float4 a = *(const float4*)(A + (size_t)(m0 + row) * lda + k0 + cc);
      As[cc + 0][row] = a.x; As[cc + 1][row] = a.y;
      As[cc + 2][row] = a.z; As[cc + 3][row] = a.w;
    }
#pragma unroll
    for (int it = 0; it < 2; ++it) {  // stage B 32x64
      int flat = it * 256 + tid;
      int kr = flat >> 4, cc = (flat & 15) * 4;
      const float4 bv = *(const float4*)(Bp + (size_t)(k0 + kr) * ldb + cc);
      *(float4*)&Bs[kr][cc] = bv;
    }
    __syncthreads();
#pragma unroll
    for (int kk = 0; kk < 32; ++kk) {
      const float4 a4 = *(const float4*)&As[kk][ty * 4];
      const float4 b4 = *(const float4*)&Bs[kk][tx * 4];
      acc[0][0] += a4.x * b4.x; acc[0][1] += a4.x * b4.y;
      acc[0][2] += a4.x * b4.z; acc[0][3] += a4.x * b4.w;
      acc[1][0] += a4.y * b4.x; acc[1][1] += a4.y * b4.y;
      acc[1][2] += a4.y * b4.z; acc[1][3] += a4.y * b4.w;
      acc[2][0] += a4.z * b4.x; acc[2][1] += a4.z * b4.y;
      acc[2][2] += a4.z * b4.z; acc[2][3] += a4.z * b4.w;
      acc[3][0] += a4.w * b4.x; acc[3][1] += a4.w * b4.y;
      acc[3][2] += a4.w * b4.z; acc[3][3] += a4.w * b4.w;
    }
  }

  const float4 bias4 = *(const float4*)(bias + n0 + tx * 4);
#pragma unroll
  for (int i = 0; i < 4; ++i) {
    const int row = m0 + ty * 4 + i;
    float4 r;
    r.x = acc[i][0] + bias4.x;
    r.y = acc[i][1] + bias4.y;
    r.z = acc[i][2] + bias4.z;
    r.w = acc[i][3] + bias4.w;
    float* cp = C + (size_t)row * ldc + n0 + tx * 4;
    if (EPI == 1) {
      r.x = gelu_new(r.x); r.y = gelu_new(r.y);
      r.z = gelu_new(r.z); r.w = gelu_new(r.w);
    }
    if (EPI == 2) {
      const float4 ad = *(const float4*)(addend + (size_t)row * ldc + n0 + tx * 4);
      r.x += ad.x; r.y += ad.y; r.z += ad.z; r.w += ad.w;
    }
    if (EPI == 3) {
      const float4 old = *(const float4*)cp;
      r.x += old.x; r.y += old.y; r.z += old.z; r.w += old.w;
    }
    *(float4*)cp = r;
  }
}

// ---------------------------------------------------------------- Attention
// Causal flash-style. Block = 4 waves; each wave owns 8 consecutive queries of
// one (b,h). The block cooperatively stages a 64-key K chunk in LDS (shared by
// all 4 waves). Score phase: lane = key (rows of Ks), Q broadcast from LDS.
// Softmax: online (running m, L) with cross-lane reductions. PV: lane = dim,
// p broadcast through padded per-wave LDS, V read coalesced from global.
__global__ __launch_bounds__(256)
void attn_kernel(const float* __restrict__ Qm, const float* __restrict__ Km,
                 const float* __restrict__ Vm, float* __restrict__ Zm) {
  __shared__ float Ks[64][68];      // shared K chunk: [key][d], padded
  __shared__ float Qs[4][8][68];    // per-wave Q tile
  __shared__ float Ps[4][64][12];   // per-wave p values: [key][query]

  const int tid = threadIdx.x, wid = tid >> 6, lane = tid & 63;
  const int bh = blockIdx.x >> 6;            // 0..31  (b*16 + h)
  const int h = bh & 15, b = bh >> 4;
  const int qt = (blockIdx.x & 63) * 4 + wid;  // q-tile 0..255
  const int q0 = qt * 8;
  const int qmax = q0 + 7;
  const size_t bh_off = (size_t)b * (SEQ * DMODEL) + (size_t)h * DHEAD;
  // element (b,s,h,d) lives at bh_off + s*1024 + d

  float qv[8];
#pragma unroll
  for (int i = 0; i < 8; ++i)
    qv[i] = Qm[bh_off + (size_t)(q0 + i) * DMODEL + lane];
#pragma unroll
  for (int i = 0; i < 8; ++i) Qs[wid][i][lane] = qv[i];
  __syncthreads();

  float m[8], L[8], o[8];
#pragma unroll
  for (int i = 0; i < 8; ++i) { m[i] = -3.0e38f; L[i] = 0.0f; o[i] = 0.0f; }

  const int nch = ((blockIdx.x & 63) * 32 + 31) / 64 + 1;  // uniform in block
  for (int ch = 0; ch < nch; ++ch) {
    const int j0 = ch * 64;
    __syncthreads();  // prior chunk fully consumed before overwrite
#pragma unroll
    for (int it = 0; it < 4; ++it) {  // cooperative K-chunk stage (coalesced)
      int flat = it * 256 + tid;      // 0..1023 float4 units
      int jj = flat >> 4, cc = (flat & 15) * 4;
      const float4 kv = *(const float4*)&Km[bh_off + (size_t)(j0 + jj) * DMODEL + cc];
      *(float4*)&Ks[jj][cc] = kv;
    }
    __syncthreads();

    if (j0 <= qmax) {
      // ---- scores: lane = key (j0+lane)
      float s[8] = {0, 0, 0, 0, 0, 0, 0, 0};
#pragma unroll
      for (int d4 = 0; d4 < 16; ++d4) {
        const float4 kv4 = *(const float4*)&Ks[lane][d4 * 4];
#pragma unroll
        for (int i = 0; i < 8; ++i) {
          const float4 q4 = *(const float4*)&Qs[wid][i][d4 * 4];  // broadcast
          s[i] += kv4.x * q4.x + kv4.y * q4.y + kv4.z * q4.z + kv4.w * q4.w;
        }
      }
      const int key = j0 + lane;
      float pv[8], cf[8];
#pragma unroll
      for (int i = 0; i < 8; ++i) {
        float si = (key <= q0 + i) ? s[i] * 0.125f : -3.0e38f;  // /sqrt(64), causal
        float mx = wave_reduce_max(si);
        float mn = fmaxf(m[i], mx);
        float c = __expf(m[i] - mn);
        float p = __expf(si - mn);
        float sum = wave_reduce_sum(p);
        L[i] = L[i] * c + sum;
        m[i] = mn; cf[i] = c; pv[i] = p;
      }
      // stash p (per-wave region; DS ops of one wave complete in order)
      *(float4*)&Ps[wid][lane][0] = make_float4(pv[0], pv[1], pv[2], pv[3]);
      *(float4*)&Ps[wid][lane][4] = make_float4(pv[4], pv[5], pv[6], pv[7]);
      // ---- PV: lane = dim
#pragma unroll
      for (int i = 0; i < 8; ++i) o[i] *= cf[i];
#pragma unroll 4
      for (int kk = 0; kk < 64; ++kk) {
        const float vd = Vm[bh_off + (size_t)(j0 + kk) * DMODEL + lane];
        const float4 p0 = *(const float4*)&Ps[wid][kk][0];  // broadcast
        const float4 p1 = *(const float4*)&Ps[wid][kk][4];
        o[0] += p0.x * vd; o[1] += p0.y * vd; o[2] += p0.z * vd; o[3] += p0.w * vd;
        o[4] += p1.x * vd; o[5] += p1.y * vd; o[6] += p1.z * vd; o[7] += p1.w * vd;
      }
    }
  }
#pragma unroll
  for (int i = 0; i < 8; ++i)
    Zm[bh_off + (size_t)(q0 + i) * DMODEL + lane] = o[i] / L[i];
}

// ---------------------------------------------------------------- launch
extern "C" void kernel_launch(void* const* d_in, const int* in_sizes, int n_in,
                              void* d_out, int out_size, void* d_ws, size_t ws_size,
                              hipStream_t stream) {
  const float* resid_pre = (const float*)d_in[0];
  const float* ln1_w = (const float*)d_in[1];
  const float* ln1_b = (const float*)d_in[2];
  const float* W_Q = (const float*)d_in[3];
  const float* W_K = (const float*)d_in[4];
  const float* W_V = (const float*)d_in[5];
  const float* W_O = (const float*)d_in[6];
  const float* b_Q = (const float*)d_in[7];
  const float* b_K = (const float*)d_in[8];
  const float* b_V = (const float*)d_in[9];
  const float* b_O = (const float*)d_in[10];
  const float* ln2_w = (const float*)d_in[11];
  const float* ln2_b = (const float*)d_in[12];
  const float* W_in = (const float*)d_in[13];
  const float* b_in = (const float*)d_in[14];
  const float* W_out = (const float*)d_in[15];
  const float* b_out = (const float*)d_in[16];

  float* out = (float*)d_out;
  float* ws = (float*)d_ws;
  // Workspace map (floats). Total 20M floats = 80 MB.
  float* xln = ws;                    // [4096,1024]  LN1 out, later LN2 out
  float* q   = ws + (1u << 22);       // [4096,1024]  Q, then attn-Z in place
  float* k   = ws + (2u << 22);       // [4096,1024]
  float* v   = ws + (3u << 22);       // [4096,1024]
  float* hid = ws + (1u << 22);       // [4096,4096]  overlaps dead q/k/v
  (void)in_sizes; (void)n_in; (void)out_size; (void)ws_size;

  // LN1
  ln_kernel<<<ROWS, 256, 0, stream>>>(resid_pre, ln1_w, ln1_b, xln);
  // QKV projections (per-head 64-col panels of W_[QKV][H,D,DH])
  dim3 gqkv(ROWS / 64, (NHEAD * DHEAD) / 64);
  gemm64<0><<<gqkv, 256, 0, stream>>>(xln, DMODEL, W_Q, (long long)DMODEL * DHEAD,
                                      DHEAD, b_Q, nullptr, q, DMODEL, DMODEL);
  gemm64<0><<<gqkv, 256, 0, stream>>>(xln, DMODEL, W_K, (long long)DMODEL * DHEAD,
                                      DHEAD, b_K, nullptr, k, DMODEL, DMODEL);
  gemm64<0><<<gqkv, 256, 0, stream>>>(xln, DMODEL, W_V, (long long)DMODEL * DHEAD,
                                      DHEAD, b_V, nullptr, v, DMODEL, DMODEL);
  // causal attention; Z written in place over Q
  attn_kernel<<<2048, 256, 0, stream>>>(q, k, v, q);
  // W_O projection + residual add -> d_out = resid_mid
  gemm64<2><<<gqkv, 256, 0, stream>>>(q, DMODEL, W_O, 64LL, DMODEL, b_O,
                                      resid_pre, out, DMODEL, DMODEL);
  // LN2
  ln_kernel<<<ROWS, 256, 0, stream>>>(out, ln2_w, ln2_b, xln);
  // MLP in + GELU
  dim3 gin(ROWS / 64, DMLP / 64);
  gemm64<1><<<gin, 256, 0, stream>>>(xln, DMODEL, W_in, 64LL, DMLP, b_in,
                                     nullptr, hid, DMLP, DMODEL);
  // MLP out, accumulate into resid_mid
  dim3 gout(ROWS / 64, DMODEL / 64);
  gemm64<3><<<gout, 256, 0, stream>>>(hid, DMLP, W_out, 64LL, DMODEL, b_out,
                                      nullptr, out, DMODEL, DMLP);
}

// Round 3
// 1318.490 us; speedup vs baseline: 1.9185x; 1.9185x over previous
//
#include <hip/hip_runtime.h>
#include <cstdint>
#include <cstddef>

// Problem constants (B=2, S=2048, D=1024, H=16, DH=64, DM=4096)
#define SEQ    2048
#define DMODEL 1024
#define NHEAD  16
#define DHEAD  64
#define DMLP   4096
#define ROWS   4096   // B*S

typedef __attribute__((ext_vector_type(8))) short bf16x8v;  // 8 bf16 (4 VGPRs)
typedef __attribute__((ext_vector_type(4))) float f32x4;

// ---------------------------------------------------------------- utilities
__device__ __forceinline__ float wave_reduce_sum(float v) {
#pragma unroll
  for (int off = 32; off; off >>= 1) v += __shfl_xor(v, off, 64);
  return v;
}
__device__ __forceinline__ float wave_reduce_max(float v) {
#pragma unroll
  for (int off = 32; off; off >>= 1) v = fmaxf(v, __shfl_xor(v, off, 64));
  return v;
}
__device__ __forceinline__ float gelu_new(float x) {
  // 0.5*x*(1+tanh(sqrt(2/pi)*(x+0.044715*x^3)))  (jax.nn.gelu approximate=True)
  const float c = 0.7978845608028654f;
  float inner = c * (x + 0.044715f * x * x * x);
  return 0.5f * x * (1.0f + tanhf(inner));
}
__device__ __forceinline__ unsigned short f2bf(float x) {  // RNE f32->bf16
  union { float f; unsigned u; } v; v.f = x;
  unsigned r = v.u + 0x7fffu + ((v.u >> 16) & 1u);
  return (unsigned short)(r >> 16);
}
// async global->LDS, 16B per lane (global addr per-lane; LDS base wave-uniform)
__device__ __forceinline__ void gload_lds16(const void* g, void* l) {
  __builtin_amdgcn_global_load_lds(
      (const __attribute__((address_space(1))) unsigned int*)g,
      (__attribute__((address_space(3))) unsigned int*)l, 16, 0, 0);
}

// ---------------------------------------------------------------- LayerNorm
// TransformerLens LN -> bf16 output (feeds MFMA GEMMs).
__global__ __launch_bounds__(256)
void ln_bf16_kernel(const float* __restrict__ x, const float* __restrict__ w,
                    const float* __restrict__ b, unsigned short* __restrict__ y) {
  __shared__ float sred[4];
  const int r = blockIdx.x;
  const int t = threadIdx.x;
  const int wid = t >> 6, lane = t & 63;
  const float4 v = ((const float4*)(x + (size_t)r * DMODEL))[t];

  float s = v.x + v.y + v.z + v.w;
  s = wave_reduce_sum(s);
  if (lane == 0) sred[wid] = s;
  __syncthreads();
  const float mean = (sred[0] + sred[1] + sred[2] + sred[3]) * (1.0f / DMODEL);
  __syncthreads();

  float4 c;
  c.x = v.x - mean; c.y = v.y - mean; c.z = v.z - mean; c.w = v.w - mean;
  float ss = c.x * c.x + c.y * c.y + c.z * c.z + c.w * c.w;
  ss = wave_reduce_sum(ss);
  if (lane == 0) sred[wid] = ss;
  __syncthreads();
  const float rs =
      rsqrtf((sred[0] + sred[1] + sred[2] + sred[3]) * (1.0f / DMODEL) + 1e-5f);

  const float4 wv = ((const float4*)w)[t];
  const float4 bv = ((const float4*)b)[t];
  ushort4 o;
  o.x = f2bf(c.x * rs * wv.x + bv.x);
  o.y = f2bf(c.y * rs * wv.y + bv.y);
  o.z = f2bf(c.z * rs * wv.z + bv.z);
  o.w = f2bf(c.w * rs * wv.w + bv.w);
  ((ushort4*)(y + (size_t)r * DMODEL))[t] = o;
}

// ------------------------------------------------- weight convert/transpose
// Generic 64x64-tile transpose + f32->bf16: dst[c][r] = src[r][c].
__global__ __launch_bounds__(256)
void transpose_cvt(const float* __restrict__ src, unsigned short* __restrict__ dst,
                   int ld_src, int ld_dst) {
  __shared__ float t[64][68];
  const int r0 = blockIdx.y * 64, c0 = blockIdx.x * 64;
  const int tid = threadIdx.x;
  const int c4 = (tid & 15) * 4, r = tid >> 4;
#pragma unroll
  for (int p = 0; p < 4; ++p) {
    const float4 v = *(const float4*)(src + (size_t)(r0 + r + p * 16) * ld_src + c0 + c4);
    *(float4*)&t[r + p * 16][c4] = v;
  }
  __syncthreads();
  const int r4 = (tid & 15) * 4, c = tid >> 4;
#pragma unroll
  for (int p = 0; p < 4; ++p) {
    const int cc = c + p * 16;
    ushort4 o;
    o.x = f2bf(t[r4 + 0][cc]);
    o.y = f2bf(t[r4 + 1][cc]);
    o.z = f2bf(t[r4 + 2][cc]);
    o.w = f2bf(t[r4 + 3][cc]);
    *(ushort4*)(dst + (size_t)(c0 + cc) * ld_dst + r0 + r4) = o;
  }
}

// W_{Q,K,V}[H, D, DH] f32 -> Bt[h*64+dh][d] bf16 (3 weights, contiguous out).
__global__ __launch_bounds__(256)
void cvt_wqkv(const float* __restrict__ Wq, const float* __restrict__ Wk,
              const float* __restrict__ Wv, unsigned short* __restrict__ out) {
  __shared__ float t[64][68];
  const float* src = (blockIdx.z == 0) ? Wq : (blockIdx.z == 1) ? Wk : Wv;
  unsigned short* dst = out + (size_t)blockIdx.z * (DMODEL * NHEAD * DHEAD);
  const int h = blockIdx.y, d0 = blockIdx.x * 64;
  const int tid = threadIdx.x;
  const int c4 = (tid & 15) * 4, r = tid >> 4;
#pragma unroll
  for (int p = 0; p < 4; ++p) {
    const float4 v = *(const float4*)(src + (size_t)h * (DMODEL * DHEAD) +
                                      (size_t)(d0 + r + p * 16) * DHEAD + c4);
    *(float4*)&t[r + p * 16][c4] = v;
  }
  __syncthreads();
  const int r4 = (tid & 15) * 4, c = tid >> 4;
#pragma unroll
  for (int p = 0; p < 4; ++p) {
    const int cc = c + p * 16;  // dh index
    ushort4 o;
    o.x = f2bf(t[r4 + 0][cc]);
    o.y = f2bf(t[r4 + 1][cc]);
    o.z = f2bf(t[r4 + 2][cc]);
    o.w = f2bf(t[r4 + 3][cc]);
    *(ushort4*)(dst + (size_t)(h * 64 + cc) * DMODEL + d0 + r4) = o;
  }
}

// elementwise f32 -> bf16 (for attention output Z)
__global__ __launch_bounds__(256)
void cvt_elem(const float* __restrict__ src, unsigned short* __restrict__ dst, int n4) {
  const int i = blockIdx.x * 256 + threadIdx.x;
  if (i < n4) {
    const float4 v = ((const float4*)src)[i];
    ushort4 o;
    o.x = f2bf(v.x); o.y = f2bf(v.y); o.z = f2bf(v.z); o.w = f2bf(v.w);
    ((ushort4*)dst)[i] = o;
  }
}

// ---------------------------------------------------------------- MFMA GEMM
// C[M x N] = A[M x K](bf16,row-major) @ Bt[N x K](bf16,row-major)^T + bias.
// m97 structure: 128x128 tile, BK=32, 4 waves, global_load_lds w16, 2 barriers.
// EPI: 0 = f32 store; 1 = bf16 gelu store; 2 = f32 + addend; 3 = f32 accum.
template <int EPI>
__global__ __launch_bounds__(256)
void gemm_bf16(const unsigned short* __restrict__ A,
               const unsigned short* __restrict__ Bt,
               const float* __restrict__ bias, const float* __restrict__ addend,
               void* __restrict__ Cout, int ldc, int K) {
  __shared__ unsigned short As[128 * 32];  // [row][k] linear, rows of 64B
  __shared__ unsigned short Bs[128 * 32];
  const int tid = threadIdx.x;
  const int w = tid >> 6, lane = tid & 63;
  const int wr = w >> 1, wc = w & 1;           // wave -> 64x64 quadrant
  const int m0 = blockIdx.x * 128, n0 = blockIdx.y * 128;

  f32x4 acc[4][4];
#pragma unroll
  for (int m = 0; m < 4; ++m)
#pragma unroll
    for (int n = 0; n < 4; ++n) acc[m][n] = (f32x4){0.f, 0.f, 0.f, 0.f};

  const int srow = w * 32 + (lane >> 2);       // staging row within tile
  const int scol = (lane & 3) * 8;             // staging k-offset (8 bf16 = 16B)

  for (int k0 = 0; k0 < K; k0 += 32) {
    __syncthreads();  // all waves done reading previous tile
#pragma unroll
    for (int it = 0; it < 2; ++it) {
      const int row = srow + it * 16;
      gload_lds16(A + (size_t)(m0 + row) * K + k0 + scol,
                  &As[(w * 32 + it * 16) * 32]);
      gload_lds16(Bt + (size_t)(n0 + row) * K + k0 + scol,
                  &Bs[(w * 32 + it * 16) * 32]);
    }
    __syncthreads();  // staging complete (vmcnt drained at barrier)

    bf16x8v af[4], bf[4];
#pragma unroll
    for (int m = 0; m < 4; ++m)
      af[m] = *(const bf16x8v*)&As[(wr * 64 + m * 16 + (lane & 15)) * 32 + (lane >> 4) * 8];
#pragma unroll
    for (int n = 0; n < 4; ++n)
      bf[n] = *(const bf16x8v*)&Bs[(wc * 64 + n * 16 + (lane & 15)) * 32 + (lane >> 4) * 8];
#pragma unroll
    for (int m = 0; m < 4; ++m)
#pragma unroll
      for (int n = 0; n < 4; ++n)
        acc[m][n] = __builtin_amdgcn_mfma_f32_16x16x32_bf16(af[m], bf[n], acc[m][n], 0, 0, 0);
  }

  // epilogue: C/D layout col = lane&15, row = (lane>>4)*4 + reg  [m89]
#pragma unroll
  for (int m = 0; m < 4; ++m) {
    const int row = m0 + wr * 64 + m * 16 + (lane >> 4) * 4;
#pragma unroll
    for (int n = 0; n < 4; ++n) {
      const int col = n0 + wc * 64 + n * 16 + (lane & 15);
      const float bcol = bias[col];
      const f32x4 a = acc[m][n];
#pragma unroll
      for (int r = 0; r < 4; ++r) {
        const float val = a[r] + bcol;
        const size_t off = (size_t)(row + r) * ldc + col;
        if (EPI == 0) {
          ((float*)Cout)[off] = val;
        } else if (EPI == 1) {
          ((unsigned short*)Cout)[off] = f2bf(gelu_new(val));
        } else if (EPI == 2) {
          ((float*)Cout)[off] = val + addend[off];
        } else {
          ((float*)Cout)[off] += val;
        }
      }
    }
  }
}

// ---------------------------------------------------------------- Attention
// (unchanged from round 1 — fp32 flash-style; next-round target)
__global__ __launch_bounds__(256)
void attn_kernel(const float* __restrict__ Qm, const float* __restrict__ Km,
                 const float* __restrict__ Vm, float* __restrict__ Zm) {
  __shared__ float Ks[64][68];      // shared K chunk: [key][d], padded
  __shared__ float Qs[4][8][68];    // per-wave Q tile
  __shared__ float Ps[4][64][12];   // per-wave p values: [key][query]

  const int tid = threadIdx.x, wid = tid >> 6, lane = tid & 63;
  const int bh = blockIdx.x >> 6;            // 0..31  (b*16 + h)
  const int h = bh & 15, b = bh >> 4;
  const int qt = (blockIdx.x & 63) * 4 + wid;  // q-tile 0..255
  const int q0 = qt * 8;
  const int qmax = q0 + 7;
  const size_t bh_off = (size_t)b * (SEQ * DMODEL) + (size_t)h * DHEAD;

  float qv[8];
#pragma unroll
  for (int i = 0; i < 8; ++i)
    qv[i] = Qm[bh_off + (size_t)(q0 + i) * DMODEL + lane];
#pragma unroll
  for (int i = 0; i < 8; ++i) Qs[wid][i][lane] = qv[i];
  __syncthreads();

  float m[8], L[8], o[8];
#pragma unroll
  for (int i = 0; i < 8; ++i) { m[i] = -3.0e38f; L[i] = 0.0f; o[i] = 0.0f; }

  const int nch = ((blockIdx.x & 63) * 32 + 31) / 64 + 1;  // uniform in block
  for (int ch = 0; ch < nch; ++ch) {
    const int j0 = ch * 64;
    __syncthreads();
#pragma unroll
    for (int it = 0; it < 4; ++it) {
      int flat = it * 256 + tid;
      int jj = flat >> 4, cc = (flat & 15) * 4;
      const float4 kv = *(const float4*)&Km[bh_off + (size_t)(j0 + jj) * DMODEL + cc];
      *(float4*)&Ks[jj][cc] = kv;
    }
    __syncthreads();

    if (j0 <= qmax) {
      float s[8] = {0, 0, 0, 0, 0, 0, 0, 0};
#pragma unroll
      for (int d4 = 0; d4 < 16; ++d4) {
        const float4 kv4 = *(const float4*)&Ks[lane][d4 * 4];
#pragma unroll
        for (int i = 0; i < 8; ++i) {
          const float4 q4 = *(const float4*)&Qs[wid][i][d4 * 4];
          s[i] += kv4.x * q4.x + kv4.y * q4.y + kv4.z * q4.z + kv4.w * q4.w;
        }
      }
      const int key = j0 + lane;
      float pv[8], cf[8];
#pragma unroll
      for (int i = 0; i < 8; ++i) {
        float si = (key <= q0 + i) ? s[i] * 0.125f : -3.0e38f;
        float mx = wave_reduce_max(si);
        float mn = fmaxf(m[i], mx);
        float c = __expf(m[i] - mn);
        float p = __expf(si - mn);
        float sum = wave_reduce_sum(p);
        L[i] = L[i] * c + sum;
        m[i] = mn; cf[i] = c; pv[i] = p;
      }
      *(float4*)&Ps[wid][lane][0] = make_float4(pv[0], pv[1], pv[2], pv[3]);
      *(float4*)&Ps[wid][lane][4] = make_float4(pv[4], pv[5], pv[6], pv[7]);
#pragma unroll
      for (int i = 0; i < 8; ++i) o[i] *= cf[i];
#pragma unroll 4
      for (int kk = 0; kk < 64; ++kk) {
        const float vd = Vm[bh_off + (size_t)(j0 + kk) * DMODEL + lane];
        const float4 p0 = *(const float4*)&Ps[wid][kk][0];
        const float4 p1 = *(const float4*)&Ps[wid][kk][4];
        o[0] += p0.x * vd; o[1] += p0.y * vd; o[2] += p0.z * vd; o[3] += p0.w * vd;
        o[4] += p1.x * vd; o[5] += p1.y * vd; o[6] += p1.z * vd; o[7] += p1.w * vd;
      }
    }
  }
#pragma unroll
  for (int i = 0; i < 8; ++i)
    Zm[bh_off + (size_t)(q0 + i) * DMODEL + lane] = o[i] / L[i];
}

// ---------------------------------------------------------------- launch
extern "C" void kernel_launch(void* const* d_in, const int* in_sizes, int n_in,
                              void* d_out, int out_size, void* d_ws, size_t ws_size,
                              hipStream_t stream) {
  const float* resid_pre = (const float*)d_in[0];
  const float* ln1_w = (const float*)d_in[1];
  const float* ln1_b = (const float*)d_in[2];
  const float* W_Q = (const float*)d_in[3];
  const float* W_K = (const float*)d_in[4];
  const float* W_V = (const float*)d_in[5];
  const float* W_O = (const float*)d_in[6];
  const float* b_Q = (const float*)d_in[7];
  const float* b_K = (const float*)d_in[8];
  const float* b_V = (const float*)d_in[9];
  const float* b_O = (const float*)d_in[10];
  const float* ln2_w = (const float*)d_in[11];
  const float* ln2_b = (const float*)d_in[12];
  const float* W_in = (const float*)d_in[13];
  const float* b_in = (const float*)d_in[14];
  const float* W_out = (const float*)d_in[15];
  const float* b_out = (const float*)d_in[16];
  (void)in_sizes; (void)n_in; (void)out_size; (void)ws_size;

  float* out = (float*)d_out;
  char* w8 = (char*)d_ws;
  // Workspace map (80 MB total):
  //  [0,8M)    xln_b (LN1 out, then Zb, then LN2 out)  bf16 [4096,1024]
  //  [8,14M)   WQt/WKt/WVt  bf16 [1024,1024] x3 (B^T layout)
  //  [14,16M)  WOt   bf16 [1024,1024]
  //  [16,24M)  Wint  bf16 [4096,1024]
  //  [24,32M)  Woutt bf16 [1024,4096]
  //  [32,48M)  q f32 [4096,1024]   -- after attn: dead once Zb made
  //  [48,64M)  k f32               -- hid_b bf16 [4096,4096] overlaps 32..64M
  //  [64,80M)  v f32
  unsigned short* xln_b = (unsigned short*)(w8);
  unsigned short* Zb    = (unsigned short*)(w8);
  unsigned short* WQt   = (unsigned short*)(w8 + (8u << 20));
  unsigned short* WOt   = (unsigned short*)(w8 + (14u << 20));
  unsigned short* Wint  = (unsigned short*)(w8 + (16u << 20));
  unsigned short* Woutt = (unsigned short*)(w8 + (24u << 20));
  float* q = (float*)(w8 + (32u << 20));
  float* k = (float*)(w8 + (48u << 20));
  float* v = (float*)(w8 + (64u << 20));
  unsigned short* hid_b = (unsigned short*)(w8 + (32u << 20));

  // weight conversions (run every call; d_ws is re-poisoned)
  cvt_wqkv<<<dim3(16, 16, 3), 256, 0, stream>>>(W_Q, W_K, W_V, WQt);
  transpose_cvt<<<dim3(16, 16), 256, 0, stream>>>(W_O, WOt, DMODEL, DMODEL);
  transpose_cvt<<<dim3(64, 16), 256, 0, stream>>>(W_in, Wint, DMLP, DMODEL);
  transpose_cvt<<<dim3(16, 64), 256, 0, stream>>>(W_out, Woutt, DMODEL, DMLP);

  // LN1 -> bf16
  ln_bf16_kernel<<<ROWS, 256, 0, stream>>>(resid_pre, ln1_w, ln1_b, xln_b);
  // QKV projections (fp32 out for fp32 attention)
  dim3 g1024(ROWS / 128, 1024 / 128);
  gemm_bf16<0><<<g1024, 256, 0, stream>>>(xln_b, WQt, b_Q, nullptr, q, DMODEL, DMODEL);
  gemm_bf16<0><<<g1024, 256, 0, stream>>>(xln_b, WQt + (1u << 20), b_K, nullptr, k, DMODEL, DMODEL);
  gemm_bf16<0><<<g1024, 256, 0, stream>>>(xln_b, WQt + (2u << 20), b_V, nullptr, v, DMODEL, DMODEL);
  // causal attention; Z written in place over Q
  attn_kernel<<<2048, 256, 0, stream>>>(q, k, v, q);
  // Z -> bf16
  cvt_elem<<<(ROWS * DMODEL / 4) / 256, 256, 0, stream>>>(q, Zb, ROWS * DMODEL / 4);
  // W_O projection + bias + residual -> d_out = resid_mid
  gemm_bf16<2><<<g1024, 256, 0, stream>>>(Zb, WOt, b_O, resid_pre, out, DMODEL, DMODEL);
  // LN2 -> bf16
  ln_bf16_kernel<<<ROWS, 256, 0, stream>>>(out, ln2_w, ln2_b, xln_b);
  // MLP in + GELU -> bf16 hid
  dim3 gin(ROWS / 128, DMLP / 128);
  gemm_bf16<1><<<gin, 256, 0, stream>>>(xln_b, Wint, b_in, nullptr, hid_b, DMLP, DMODEL);
  // MLP out, accumulate into resid_mid in d_out
  gemm_bf16<3><<<g1024, 256, 0, stream>>>(hid_b, Woutt, b_out, nullptr, out, DMODEL, DMLP);
}

// Round 4
// 638.600 us; speedup vs baseline: 3.9611x; 2.0647x over previous
//
#include <hip/hip_runtime.h>
#include <cstdint>
#include <cstddef>

// Problem constants (B=2, S=2048, D=1024, H=16, DH=64, DM=4096)
#define SEQ    2048
#define DMODEL 1024
#define NHEAD  16
#define DHEAD  64
#define DMLP   4096
#define ROWS   4096   // B*S

typedef __attribute__((ext_vector_type(8))) short bf16x8v;  // 8 bf16 (4 VGPRs)
typedef __attribute__((ext_vector_type(4))) float f32x4;

// ---------------------------------------------------------------- utilities
__device__ __forceinline__ float wave_reduce_sum(float v) {
#pragma unroll
  for (int off = 32; off; off >>= 1) v += __shfl_xor(v, off, 64);
  return v;
}
__device__ __forceinline__ float gelu_new(float x) {
  // 0.5*x*(1+tanh(sqrt(2/pi)*(x+0.044715*x^3)))  (jax.nn.gelu approximate=True)
  const float c = 0.7978845608028654f;
  float inner = c * (x + 0.044715f * x * x * x);
  return 0.5f * x * (1.0f + tanhf(inner));
}
__device__ __forceinline__ unsigned short f2bf(float x) {  // RNE f32->bf16
  union { float f; unsigned u; } v; v.f = x;
  unsigned r = v.u + 0x7fffu + ((v.u >> 16) & 1u);
  return (unsigned short)(r >> 16);
}
// async global->LDS, 16B per lane (global addr per-lane; LDS base wave-uniform)
__device__ __forceinline__ void gload_lds16(const void* g, void* l) {
  __builtin_amdgcn_global_load_lds(
      (const __attribute__((address_space(1))) unsigned int*)g,
      (__attribute__((address_space(3))) unsigned int*)l, 16, 0, 0);
}

// ---------------------------------------------------------------- LayerNorm
// TransformerLens LN -> bf16 output (feeds MFMA GEMMs).
__global__ __launch_bounds__(256)
void ln_bf16_kernel(const float* __restrict__ x, const float* __restrict__ w,
                    const float* __restrict__ b, unsigned short* __restrict__ y) {
  __shared__ float sred[4];
  const int r = blockIdx.x;
  const int t = threadIdx.x;
  const int wid = t >> 6, lane = t & 63;
  const float4 v = ((const float4*)(x + (size_t)r * DMODEL))[t];

  float s = v.x + v.y + v.z + v.w;
  s = wave_reduce_sum(s);
  if (lane == 0) sred[wid] = s;
  __syncthreads();
  const float mean = (sred[0] + sred[1] + sred[2] + sred[3]) * (1.0f / DMODEL);
  __syncthreads();

  float4 c;
  c.x = v.x - mean; c.y = v.y - mean; c.z = v.z - mean; c.w = v.w - mean;
  float ss = c.x * c.x + c.y * c.y + c.z * c.z + c.w * c.w;
  ss = wave_reduce_sum(ss);
  if (lane == 0) sred[wid] = ss;
  __syncthreads();
  const float rs =
      rsqrtf((sred[0] + sred[1] + sred[2] + sred[3]) * (1.0f / DMODEL) + 1e-5f);

  const float4 wv = ((const float4*)w)[t];
  const float4 bv = ((const float4*)b)[t];
  ushort4 o;
  o.x = f2bf(c.x * rs * wv.x + bv.x);
  o.y = f2bf(c.y * rs * wv.y + bv.y);
  o.z = f2bf(c.z * rs * wv.z + bv.z);
  o.w = f2bf(c.w * rs * wv.w + bv.w);
  ((ushort4*)(y + (size_t)r * DMODEL))[t] = o;
}

// ------------------------------------------------- weight convert/transpose
// Generic 64x64-tile transpose + f32->bf16: dst[c][r] = src[r][c].
__global__ __launch_bounds__(256)
void transpose_cvt(const float* __restrict__ src, unsigned short* __restrict__ dst,
                   int ld_src, int ld_dst) {
  __shared__ float t[64][68];
  const int r0 = blockIdx.y * 64, c0 = blockIdx.x * 64;
  const int tid = threadIdx.x;
  const int c4 = (tid & 15) * 4, r = tid >> 4;
#pragma unroll
  for (int p = 0; p < 4; ++p) {
    const float4 v = *(const float4*)(src + (size_t)(r0 + r + p * 16) * ld_src + c0 + c4);
    *(float4*)&t[r + p * 16][c4] = v;
  }
  __syncthreads();
  const int r4 = (tid & 15) * 4, c = tid >> 4;
#pragma unroll
  for (int p = 0; p < 4; ++p) {
    const int cc = c + p * 16;
    ushort4 o;
    o.x = f2bf(t[r4 + 0][cc]);
    o.y = f2bf(t[r4 + 1][cc]);
    o.z = f2bf(t[r4 + 2][cc]);
    o.w = f2bf(t[r4 + 3][cc]);
    *(ushort4*)(dst + (size_t)(c0 + cc) * ld_dst + r0 + r4) = o;
  }
}

// W_{Q,K,V}[H, D, DH] f32 -> Bt[h*64+dh][d] bf16 (3 weights, contiguous out).
__global__ __launch_bounds__(256)
void cvt_wqkv(const float* __restrict__ Wq, const float* __restrict__ Wk,
              const float* __restrict__ Wv, unsigned short* __restrict__ out) {
  __shared__ float t[64][68];
  const float* src = (blockIdx.z == 0) ? Wq : (blockIdx.z == 1) ? Wk : Wv;
  unsigned short* dst = out + (size_t)blockIdx.z * (DMODEL * NHEAD * DHEAD);
  const int h = blockIdx.y, d0 = blockIdx.x * 64;
  const int tid = threadIdx.x;
  const int c4 = (tid & 15) * 4, r = tid >> 4;
#pragma unroll
  for (int p = 0; p < 4; ++p) {
    const float4 v = *(const float4*)(src + (size_t)h * (DMODEL * DHEAD) +
                                      (size_t)(d0 + r + p * 16) * DHEAD + c4);
    *(float4*)&t[r + p * 16][c4] = v;
  }
  __syncthreads();
  const int r4 = (tid & 15) * 4, c = tid >> 4;
#pragma unroll
  for (int p = 0; p < 4; ++p) {
    const int cc = c + p * 16;  // dh index
    ushort4 o;
    o.x = f2bf(t[r4 + 0][cc]);
    o.y = f2bf(t[r4 + 1][cc]);
    o.z = f2bf(t[r4 + 2][cc]);
    o.w = f2bf(t[r4 + 3][cc]);
    *(ushort4*)(dst + (size_t)(h * 64 + cc) * DMODEL + d0 + r4) = o;
  }
}

// ---------------------------------------------------------------- MFMA GEMM
// C[M x N] = A[M x K](bf16,row-major) @ Bt[N x K](bf16,row-major)^T + bias.
// m97 structure: 128x128 tile, BK=32, 4 waves, global_load_lds w16, 2 barriers.
// EPI: 0 = f32 store; 1 = bf16 gelu store; 2 = f32 + addend; 3 = f32 accum;
//      4 = bf16 TRANSPOSED store (Cout[col][ldc] layout, packed ushort4);
//      5 = bf16 store.
template <int EPI>
__global__ __launch_bounds__(256)
void gemm_bf16(const unsigned short* __restrict__ A,
               const unsigned short* __restrict__ Bt,
               const float* __restrict__ bias, const float* __restrict__ addend,
               void* __restrict__ Cout, int ldc, int K) {
  __shared__ unsigned short As[128 * 32];  // [row][k] linear, rows of 64B
  __shared__ unsigned short Bs[128 * 32];
  const int tid = threadIdx.x;
  const int w = tid >> 6, lane = tid & 63;
  const int wr = w >> 1, wc = w & 1;           // wave -> 64x64 quadrant
  const int m0 = blockIdx.x * 128, n0 = blockIdx.y * 128;

  f32x4 acc[4][4];
#pragma unroll
  for (int m = 0; m < 4; ++m)
#pragma unroll
    for (int n = 0; n < 4; ++n) acc[m][n] = (f32x4){0.f, 0.f, 0.f, 0.f};

  const int srow = w * 32 + (lane >> 2);       // staging row within tile
  const int scol = (lane & 3) * 8;             // staging k-offset (8 bf16 = 16B)

  for (int k0 = 0; k0 < K; k0 += 32) {
    __syncthreads();  // all waves done reading previous tile
#pragma unroll
    for (int it = 0; it < 2; ++it) {
      const int row = srow + it * 16;
      gload_lds16(A + (size_t)(m0 + row) * K + k0 + scol,
                  &As[(w * 32 + it * 16) * 32]);
      gload_lds16(Bt + (size_t)(n0 + row) * K + k0 + scol,
                  &Bs[(w * 32 + it * 16) * 32]);
    }
    __syncthreads();  // staging complete (vmcnt drained at barrier)

    bf16x8v af[4], bf[4];
#pragma unroll
    for (int m = 0; m < 4; ++m)
      af[m] = *(const bf16x8v*)&As[(wr * 64 + m * 16 + (lane & 15)) * 32 + (lane >> 4) * 8];
#pragma unroll
    for (int n = 0; n < 4; ++n)
      bf[n] = *(const bf16x8v*)&Bs[(wc * 64 + n * 16 + (lane & 15)) * 32 + (lane >> 4) * 8];
#pragma unroll
    for (int m = 0; m < 4; ++m)
#pragma unroll
      for (int n = 0; n < 4; ++n)
        acc[m][n] = __builtin_amdgcn_mfma_f32_16x16x32_bf16(af[m], bf[n], acc[m][n], 0, 0, 0);
  }

  // epilogue: C/D layout col = lane&15, row = (lane>>4)*4 + reg  [m89]
#pragma unroll
  for (int m = 0; m < 4; ++m) {
    const int row = m0 + wr * 64 + m * 16 + (lane >> 4) * 4;
#pragma unroll
    for (int n = 0; n < 4; ++n) {
      const int col = n0 + wc * 64 + n * 16 + (lane & 15);
      const float bcol = bias[col];
      const f32x4 a = acc[m][n];
      if (EPI == 4) {
        // transposed bf16 store: 4 contiguous rows in dst row `col`
        ushort4 o;
        o.x = f2bf(a[0] + bcol); o.y = f2bf(a[1] + bcol);
        o.z = f2bf(a[2] + bcol); o.w = f2bf(a[3] + bcol);
        *(ushort4*)((unsigned short*)Cout + (size_t)col * ldc + row) = o;
      } else {
#pragma unroll
        for (int r = 0; r < 4; ++r) {
          const float val = a[r] + bcol;
          const size_t off = (size_t)(row + r) * ldc + col;
          if (EPI == 0) {
            ((float*)Cout)[off] = val;
          } else if (EPI == 1) {
            ((unsigned short*)Cout)[off] = f2bf(gelu_new(val));
          } else if (EPI == 2) {
            ((float*)Cout)[off] = val + addend[off];
          } else if (EPI == 3) {
            ((float*)Cout)[off] += val;
          } else {  // EPI == 5
            ((unsigned short*)Cout)[off] = f2bf(val);
          }
        }
      }
    }
  }
}

// ---------------------------------------------------------------- Attention
// Causal MFMA flash attention, bf16 inputs, fp32 accum.
// Grid: 32 (b,h) x 32 q-blocks of 64. Block = 4 waves; wave owns 16 queries.
// Per 64-key chunk: QK^T (8 MFMA, K B-frags direct from global / L2),
// online softmax in acc layout (row reduce = 4 regs + shfl_xor over 16-lane
// col group), P -> per-wave padded LDS tile -> A-frags, PV (8 MFMA, V^T
// B-frags direct from global Vt). No __syncthreads (per-wave LDS only).
__global__ __launch_bounds__(256)
void attn_mfma_kernel(const unsigned short* __restrict__ Qb,
                      const unsigned short* __restrict__ Kb,
                      const unsigned short* __restrict__ Vt,
                      unsigned short* __restrict__ Zb) {
  __shared__ unsigned short Ps[4][16][72];  // per-wave P: [qloc][key], pad->16B rows
  const int tid = threadIdx.x;
  const int w = tid >> 6, lane = tid & 63;
  const int lg = lane >> 4, lr = lane & 15;
  const int bh = blockIdx.x >> 5;          // b*16 + h
  const int qblk = blockIdx.x & 31;
  const int h = bh & 15, b = bh >> 4;
  const int q0 = qblk * 64 + w * 16;       // wave's first query (seq index)
  const size_t qk_base = (size_t)b * SEQ * DMODEL + (size_t)h * DHEAD;
  const size_t vt_base = (size_t)(h * DHEAD) * ROWS + (size_t)b * SEQ;

  // Q A-fragments: row(m)=lr -> query q0+lr, k(d) = ks*32 + lg*8 + 0..7
  bf16x8v aq[2];
#pragma unroll
  for (int ks = 0; ks < 2; ++ks)
    aq[ks] = *(const bf16x8v*)&Qb[qk_base + (size_t)(q0 + lr) * DMODEL + ks * 32 + lg * 8];

  f32x4 accz[4];
#pragma unroll
  for (int nd = 0; nd < 4; ++nd) accz[nd] = (f32x4){0.f, 0.f, 0.f, 0.f};
  float mrow[4] = {-3.0e38f, -3.0e38f, -3.0e38f, -3.0e38f};
  float Lrow[4] = {0.f, 0.f, 0.f, 0.f};

  for (int jc = 0; jc <= qblk * 64; jc += 64) {
    // ---- QK^T: scores S[q][key], col=key, row=q
    f32x4 accs[4];
#pragma unroll
    for (int n = 0; n < 4; ++n) accs[n] = (f32x4){0.f, 0.f, 0.f, 0.f};
#pragma unroll
    for (int ks = 0; ks < 2; ++ks) {
#pragma unroll
      for (int n = 0; n < 4; ++n) {
        const bf16x8v bk = *(const bf16x8v*)
            &Kb[qk_base + (size_t)(jc + n * 16 + lr) * DMODEL + ks * 32 + lg * 8];
        accs[n] = __builtin_amdgcn_mfma_f32_16x16x32_bf16(aq[ks], bk, accs[n], 0, 0, 0);
      }
    }
    // ---- online softmax; rows q = q0 + lg*4 + r (replicated across lr)
    float p[4][4], cf[4];
#pragma unroll
    for (int r = 0; r < 4; ++r) {
      const int q = q0 + lg * 4 + r;
      float sv[4], mx = -3.0e38f;
#pragma unroll
      for (int n = 0; n < 4; ++n) {
        float s = accs[n][r] * 0.125f;                      // 1/sqrt(64)
        s = (jc + n * 16 + lr <= q) ? s : -3.0e38f;          // causal
        sv[n] = s; mx = fmaxf(mx, s);
      }
#pragma unroll
      for (int off = 1; off < 16; off <<= 1) mx = fmaxf(mx, __shfl_xor(mx, off, 64));
      const float mn = fmaxf(mrow[r], mx);
      const float c0 = __expf(mrow[r] - mn);
      float sum = 0.f;
#pragma unroll
      for (int n = 0; n < 4; ++n) {
        const float pp = __expf(sv[n] - mn);
        p[n][r] = pp; sum += pp;
      }
#pragma unroll
      for (int off = 1; off < 16; off <<= 1) sum += __shfl_xor(sum, off, 64);
      Lrow[r] = Lrow[r] * c0 + sum;
      mrow[r] = mn; cf[r] = c0;
    }
#pragma unroll
    for (int nd = 0; nd < 4; ++nd)
#pragma unroll
      for (int r = 0; r < 4; ++r) accz[nd][r] *= cf[r];
    // ---- P acc-layout -> LDS -> A-fragments (same-wave DS ordering)
#pragma unroll
    for (int n = 0; n < 4; ++n)
#pragma unroll
      for (int r = 0; r < 4; ++r)
        Ps[w][lg * 4 + r][n * 16 + lr] = f2bf(p[n][r]);
    bf16x8v ap[2];
#pragma unroll
    for (int ks = 0; ks < 2; ++ks)
      ap[ks] = *(const bf16x8v*)&Ps[w][lr][ks * 32 + lg * 8];
    // ---- PV: Z[q][d] += P @ V ; B-frag row(n)=d from Vt[d][key]
#pragma unroll
    for (int ks = 0; ks < 2; ++ks) {
#pragma unroll
      for (int nd = 0; nd < 4; ++nd) {
        const bf16x8v bv = *(const bf16x8v*)
            &Vt[vt_base + (size_t)(nd * 16 + lr) * ROWS + jc + ks * 32 + lg * 8];
        accz[nd] = __builtin_amdgcn_mfma_f32_16x16x32_bf16(ap[ks], bv, accz[nd], 0, 0, 0);
      }
    }
  }
  // ---- epilogue: Z/L, bf16 store
#pragma unroll
  for (int nd = 0; nd < 4; ++nd) {
    const int col = h * DHEAD + nd * 16 + lr;
#pragma unroll
    for (int r = 0; r < 4; ++r) {
      const size_t row = (size_t)b * SEQ + q0 + lg * 4 + r;
      Zb[row * DMODEL + col] = f2bf(accz[nd][r] / Lrow[r]);
    }
  }
}

// ---------------------------------------------------------------- launch
extern "C" void kernel_launch(void* const* d_in, const int* in_sizes, int n_in,
                              void* d_out, int out_size, void* d_ws, size_t ws_size,
                              hipStream_t stream) {
  const float* resid_pre = (const float*)d_in[0];
  const float* ln1_w = (const float*)d_in[1];
  const float* ln1_b = (const float*)d_in[2];
  const float* W_Q = (const float*)d_in[3];
  const float* W_K = (const float*)d_in[4];
  const float* W_V = (const float*)d_in[5];
  const float* W_O = (const float*)d_in[6];
  const float* b_Q = (const float*)d_in[7];
  const float* b_K = (const float*)d_in[8];
  const float* b_V = (const float*)d_in[9];
  const float* b_O = (const float*)d_in[10];
  const float* ln2_w = (const float*)d_in[11];
  const float* ln2_b = (const float*)d_in[12];
  const float* W_in = (const float*)d_in[13];
  const float* b_in = (const float*)d_in[14];
  const float* W_out = (const float*)d_in[15];
  const float* b_out = (const float*)d_in[16];
  (void)in_sizes; (void)n_in; (void)out_size; (void)ws_size;

  float* out = (float*)d_out;
  char* w8 = (char*)d_ws;
  // Workspace map (64 MB used):
  //  [0,8M)    xln_b (LN1 out / LN2 out) ; Zb aliases (dead-time disjoint)
  //  [8,14M)   WQt/WKt/WVt  bf16 [1024,1024] x3 (B^T layout)
  //  [14,16M)  WOt   bf16 [1024,1024]
  //  [16,24M)  Wint  bf16 [4096,1024]
  //  [24,32M)  Woutt bf16 [1024,4096]
  //  [32,40M)  Qb bf16 [4096,1024]   \
  //  [40,48M)  Kb bf16 [4096,1024]    } dead after attn; hid_b [32,64M) reuses
  //  [48,56M)  Vt bf16 [1024,4096]   /
  unsigned short* xln_b = (unsigned short*)(w8);
  unsigned short* Zb    = (unsigned short*)(w8);
  unsigned short* WQt   = (unsigned short*)(w8 + (8u << 20));
  unsigned short* WOt   = (unsigned short*)(w8 + (14u << 20));
  unsigned short* Wint  = (unsigned short*)(w8 + (16u << 20));
  unsigned short* Woutt = (unsigned short*)(w8 + (24u << 20));
  unsigned short* Qb    = (unsigned short*)(w8 + (32u << 20));
  unsigned short* Kb    = (unsigned short*)(w8 + (40u << 20));
  unsigned short* Vt    = (unsigned short*)(w8 + (48u << 20));
  unsigned short* hid_b = (unsigned short*)(w8 + (32u << 20));

  // weight conversions (run every call; d_ws is re-poisoned)
  cvt_wqkv<<<dim3(16, 16, 3), 256, 0, stream>>>(W_Q, W_K, W_V, WQt);
  transpose_cvt<<<dim3(16, 16), 256, 0, stream>>>(W_O, WOt, DMODEL, DMODEL);
  transpose_cvt<<<dim3(64, 16), 256, 0, stream>>>(W_in, Wint, DMLP, DMODEL);
  transpose_cvt<<<dim3(16, 64), 256, 0, stream>>>(W_out, Woutt, DMODEL, DMLP);

  // LN1 -> bf16
  ln_bf16_kernel<<<ROWS, 256, 0, stream>>>(resid_pre, ln1_w, ln1_b, xln_b);
  // QKV projections -> bf16 (V directly transposed into Vt)
  dim3 g1024(ROWS / 128, 1024 / 128);
  gemm_bf16<5><<<g1024, 256, 0, stream>>>(xln_b, WQt, b_Q, nullptr, Qb, DMODEL, DMODEL);
  gemm_bf16<5><<<g1024, 256, 0, stream>>>(xln_b, WQt + (1u << 20), b_K, nullptr, Kb, DMODEL, DMODEL);
  gemm_bf16<4><<<g1024, 256, 0, stream>>>(xln_b, WQt + (2u << 20), b_V, nullptr, Vt, ROWS, DMODEL);
  // causal MFMA attention -> Zb (aliases xln_b; LN1 output is dead now)
  attn_mfma_kernel<<<1024, 256, 0, stream>>>(Qb, Kb, Vt, Zb);
  // W_O projection + bias + residual -> d_out = resid_mid
  gemm_bf16<2><<<g1024, 256, 0, stream>>>(Zb, WOt, b_O, resid_pre, out, DMODEL, DMODEL);
  // LN2 -> bf16 (overwrites Zb region after W_O consumed it)
  ln_bf16_kernel<<<ROWS, 256, 0, stream>>>(out, ln2_w, ln2_b, xln_b);
  // MLP in + GELU -> bf16 hid
  dim3 gin(ROWS / 128, DMLP / 128);
  gemm_bf16<1><<<gin, 256, 0, stream>>>(xln_b, Wint, b_in, nullptr, hid_b, DMLP, DMODEL);
  // MLP out, accumulate into resid_mid in d_out
  gemm_bf16<3><<<g1024, 256, 0, stream>>>(hid_b, Woutt, b_out, nullptr, out, DMODEL, DMLP);
}

// Round 5
// 553.897 us; speedup vs baseline: 4.5668x; 1.1529x over previous
//
#include <hip/hip_runtime.h>
#include <cstdint>
#include <cstddef>

// Problem constants (B=2, S=2048, D=1024, H=16, DH=64, DM=4096)
#define SEQ    2048
#define DMODEL 1024
#define NHEAD  16
#define DHEAD  64
#define DMLP   4096
#define ROWS   4096   // B*S

typedef __attribute__((ext_vector_type(8))) short bf16x8v;  // 8 bf16 (4 VGPRs)
typedef __attribute__((ext_vector_type(4))) float f32x4;

// ---------------------------------------------------------------- utilities
__device__ __forceinline__ float wave_reduce_sum(float v) {
#pragma unroll
  for (int off = 32; off; off >>= 1) v += __shfl_xor(v, off, 64);
  return v;
}
__device__ __forceinline__ float gelu_new(float x) {
  // 0.5*x*(1+tanh(sqrt(2/pi)*(x+0.044715*x^3)))  (jax.nn.gelu approximate=True)
  const float c = 0.7978845608028654f;
  float inner = c * (x + 0.044715f * x * x * x);
  return 0.5f * x * (1.0f + tanhf(inner));
}
__device__ __forceinline__ unsigned short f2bf(float x) {  // RNE f32->bf16
  union { float f; unsigned u; } v; v.f = x;
  unsigned r = v.u + 0x7fffu + ((v.u >> 16) & 1u);
  return (unsigned short)(r >> 16);
}
// async global->LDS, 16B per lane (global addr per-lane; LDS base wave-uniform)
__device__ __forceinline__ void gload_lds16(const void* g, void* l) {
  __builtin_amdgcn_global_load_lds(
      (const __attribute__((address_space(1))) unsigned int*)g,
      (__attribute__((address_space(3))) unsigned int*)l, 16, 0, 0);
}

// ---------------------------------------------------------------- LayerNorm
// TransformerLens LN -> bf16 output (feeds MFMA GEMMs).
__global__ __launch_bounds__(256)
void ln_bf16_kernel(const float* __restrict__ x, const float* __restrict__ w,
                    const float* __restrict__ b, unsigned short* __restrict__ y) {
  __shared__ float sred[4];
  const int r = blockIdx.x;
  const int t = threadIdx.x;
  const int wid = t >> 6, lane = t & 63;
  const float4 v = ((const float4*)(x + (size_t)r * DMODEL))[t];

  float s = v.x + v.y + v.z + v.w;
  s = wave_reduce_sum(s);
  if (lane == 0) sred[wid] = s;
  __syncthreads();
  const float mean = (sred[0] + sred[1] + sred[2] + sred[3]) * (1.0f / DMODEL);
  __syncthreads();

  float4 c;
  c.x = v.x - mean; c.y = v.y - mean; c.z = v.z - mean; c.w = v.w - mean;
  float ss = c.x * c.x + c.y * c.y + c.z * c.z + c.w * c.w;
  ss = wave_reduce_sum(ss);
  if (lane == 0) sred[wid] = ss;
  __syncthreads();
  const float rs =
      rsqrtf((sred[0] + sred[1] + sred[2] + sred[3]) * (1.0f / DMODEL) + 1e-5f);

  const float4 wv = ((const float4*)w)[t];
  const float4 bv = ((const float4*)b)[t];
  ushort4 o;
  o.x = f2bf(c.x * rs * wv.x + bv.x);
  o.y = f2bf(c.y * rs * wv.y + bv.y);
  o.z = f2bf(c.z * rs * wv.z + bv.z);
  o.w = f2bf(c.w * rs * wv.w + bv.w);
  ((ushort4*)(y + (size_t)r * DMODEL))[t] = o;
}

// ------------------------------------------------- weight convert/transpose
// Generic 64x64-tile transpose + f32->bf16: dst[c][r] = src[r][c].
__global__ __launch_bounds__(256)
void transpose_cvt(const float* __restrict__ src, unsigned short* __restrict__ dst,
                   int ld_src, int ld_dst) {
  __shared__ float t[64][68];
  const int r0 = blockIdx.y * 64, c0 = blockIdx.x * 64;
  const int tid = threadIdx.x;
  const int c4 = (tid & 15) * 4, r = tid >> 4;
#pragma unroll
  for (int p = 0; p < 4; ++p) {
    const float4 v = *(const float4*)(src + (size_t)(r0 + r + p * 16) * ld_src + c0 + c4);
    *(float4*)&t[r + p * 16][c4] = v;
  }
  __syncthreads();
  const int r4 = (tid & 15) * 4, c = tid >> 4;
#pragma unroll
  for (int p = 0; p < 4; ++p) {
    const int cc = c + p * 16;
    ushort4 o;
    o.x = f2bf(t[r4 + 0][cc]);
    o.y = f2bf(t[r4 + 1][cc]);
    o.z = f2bf(t[r4 + 2][cc]);
    o.w = f2bf(t[r4 + 3][cc]);
    *(ushort4*)(dst + (size_t)(c0 + cc) * ld_dst + r0 + r4) = o;
  }
}

// W_{Q,K,V}[H, D, DH] f32 -> Bt[h*64+dh][d] bf16 (3 weights, contiguous out).
__global__ __launch_bounds__(256)
void cvt_wqkv(const float* __restrict__ Wq, const float* __restrict__ Wk,
              const float* __restrict__ Wv, unsigned short* __restrict__ out) {
  __shared__ float t[64][68];
  const float* src = (blockIdx.z == 0) ? Wq : (blockIdx.z == 1) ? Wk : Wv;
  unsigned short* dst = out + (size_t)blockIdx.z * (DMODEL * NHEAD * DHEAD);
  const int h = blockIdx.y, d0 = blockIdx.x * 64;
  const int tid = threadIdx.x;
  const int c4 = (tid & 15) * 4, r = tid >> 4;
#pragma unroll
  for (int p = 0; p < 4; ++p) {
    const float4 v = *(const float4*)(src + (size_t)h * (DMODEL * DHEAD) +
                                      (size_t)(d0 + r + p * 16) * DHEAD + c4);
    *(float4*)&t[r + p * 16][c4] = v;
  }
  __syncthreads();
  const int r4 = (tid & 15) * 4, c = tid >> 4;
#pragma unroll
  for (int p = 0; p < 4; ++p) {
    const int cc = c + p * 16;  // dh index
    ushort4 o;
    o.x = f2bf(t[r4 + 0][cc]);
    o.y = f2bf(t[r4 + 1][cc]);
    o.z = f2bf(t[r4 + 2][cc]);
    o.w = f2bf(t[r4 + 3][cc]);
    *(ushort4*)(dst + (size_t)(h * 64 + cc) * DMODEL + d0 + r4) = o;
  }
}

// ---------------------------------------------------------------- MFMA GEMM
// C[M x N] = A[M x K](bf16,row-major) @ Bt[N x K](bf16,row-major)^T + bias.
// m97 structure: 128x128 tile, BK=32, 4 waves, global_load_lds w16, 2 barriers.
// EPI: 0 = f32 store; 1 = bf16 gelu store; 2 = f32 + addend; 3 = f32 accum;
//      4 = bf16 TRANSPOSED store (Cout[col][ldc] layout, packed ushort4);
//      5 = bf16 store.
template <int EPI>
__global__ __launch_bounds__(256)
void gemm_bf16(const unsigned short* __restrict__ A,
               const unsigned short* __restrict__ Bt,
               const float* __restrict__ bias, const float* __restrict__ addend,
               void* __restrict__ Cout, int ldc, int K) {
  __shared__ unsigned short As[128 * 32];  // [row][k] linear, rows of 64B
  __shared__ unsigned short Bs[128 * 32];
  const int tid = threadIdx.x;
  const int w = tid >> 6, lane = tid & 63;
  const int wr = w >> 1, wc = w & 1;           // wave -> 64x64 quadrant
  const int m0 = blockIdx.x * 128, n0 = blockIdx.y * 128;

  f32x4 acc[4][4];
#pragma unroll
  for (int m = 0; m < 4; ++m)
#pragma unroll
    for (int n = 0; n < 4; ++n) acc[m][n] = (f32x4){0.f, 0.f, 0.f, 0.f};

  const int srow = w * 32 + (lane >> 2);       // staging row within tile
  const int scol = (lane & 3) * 8;             // staging k-offset (8 bf16 = 16B)

  for (int k0 = 0; k0 < K; k0 += 32) {
    __syncthreads();  // all waves done reading previous tile
#pragma unroll
    for (int it = 0; it < 2; ++it) {
      const int row = srow + it * 16;
      gload_lds16(A + (size_t)(m0 + row) * K + k0 + scol,
                  &As[(w * 32 + it * 16) * 32]);
      gload_lds16(Bt + (size_t)(n0 + row) * K + k0 + scol,
                  &Bs[(w * 32 + it * 16) * 32]);
    }
    __syncthreads();  // staging complete (vmcnt drained at barrier)

    bf16x8v af[4], bf[4];
#pragma unroll
    for (int m = 0; m < 4; ++m)
      af[m] = *(const bf16x8v*)&As[(wr * 64 + m * 16 + (lane & 15)) * 32 + (lane >> 4) * 8];
#pragma unroll
    for (int n = 0; n < 4; ++n)
      bf[n] = *(const bf16x8v*)&Bs[(wc * 64 + n * 16 + (lane & 15)) * 32 + (lane >> 4) * 8];
#pragma unroll
    for (int m = 0; m < 4; ++m)
#pragma unroll
      for (int n = 0; n < 4; ++n)
        acc[m][n] = __builtin_amdgcn_mfma_f32_16x16x32_bf16(af[m], bf[n], acc[m][n], 0, 0, 0);
  }

  // epilogue: C/D layout col = lane&15, row = (lane>>4)*4 + reg  [m89]
#pragma unroll
  for (int m = 0; m < 4; ++m) {
    const int row = m0 + wr * 64 + m * 16 + (lane >> 4) * 4;
#pragma unroll
    for (int n = 0; n < 4; ++n) {
      const int col = n0 + wc * 64 + n * 16 + (lane & 15);
      const float bcol = bias[col];
      const f32x4 a = acc[m][n];
      if (EPI == 4) {
        // transposed bf16 store: 4 contiguous rows in dst row `col`
        ushort4 o;
        o.x = f2bf(a[0] + bcol); o.y = f2bf(a[1] + bcol);
        o.z = f2bf(a[2] + bcol); o.w = f2bf(a[3] + bcol);
        *(ushort4*)((unsigned short*)Cout + (size_t)col * ldc + row) = o;
      } else {
#pragma unroll
        for (int r = 0; r < 4; ++r) {
          const float val = a[r] + bcol;
          const size_t off = (size_t)(row + r) * ldc + col;
          if (EPI == 0) {
            ((float*)Cout)[off] = val;
          } else if (EPI == 1) {
            ((unsigned short*)Cout)[off] = f2bf(gelu_new(val));
          } else if (EPI == 2) {
            ((float*)Cout)[off] = val + addend[off];
          } else if (EPI == 3) {
            ((float*)Cout)[off] += val;
          } else {  // EPI == 5
            ((unsigned short*)Cout)[off] = f2bf(val);
          }
        }
      }
    }
  }
}

// ---------------------------------------------------------------- Attention
// Causal MFMA flash attention, bf16 inputs, fp32 accum. SWAPPED-operand form:
// accs = mfma(K_frag, Q_frag) -> S^T (col=q, row=key), so the 64-key softmax
// reduce is 16 in-register values + 2 shfl_xor (off 16,32); m/L/rescale are
// lane-scalars (lane's q = lane&15). PV: accz = mfma(Vt_frag, P_frag) -> Z^T
// (col=q, row=d), epilogue packs ushort4 along d.
// Load balance: 512 blocks; block pr handles qblk=pr then qblk=31-pr
// (33 chunks each, uniform). Block = 4 waves; wave owns 16 queries.
// No __syncthreads (per-wave LDS only; same-wave DS ops are ordered).
__global__ __launch_bounds__(256)
void attn_mfma_kernel(const unsigned short* __restrict__ Qb,
                      const unsigned short* __restrict__ Kb,
                      const unsigned short* __restrict__ Vt,
                      unsigned short* __restrict__ Zb) {
  __shared__ unsigned short Ps[4][16][72];  // per-wave P: [qloc][key], padded
  const int tid = threadIdx.x;
  const int w = tid >> 6, lane = tid & 63;
  const int lg = lane >> 4, lr = lane & 15;
  const int bh = blockIdx.x >> 4;          // b*16 + h
  const int pr = blockIdx.x & 15;          // pair index 0..15
  const int h = bh & 15, b = bh >> 4;
  const size_t qk_base = (size_t)b * SEQ * DMODEL + (size_t)h * DHEAD;
  const size_t vt_base = (size_t)(h * DHEAD) * ROWS + (size_t)b * SEQ;

#pragma unroll
  for (int sel = 0; sel < 2; ++sel) {
    const int qblk = sel ? (31 - pr) : pr;
    const int q0 = qblk * 64 + w * 16;     // wave's first query
    const int myq = q0 + lr;               // this lane's query (col index)

    // Q B-fragment: n(col)=lr -> query myq, k(dim) = ks*32 + lg*8 + 0..7
    bf16x8v bq[2];
#pragma unroll
    for (int ks = 0; ks < 2; ++ks)
      bq[ks] = *(const bf16x8v*)&Qb[qk_base + (size_t)myq * DMODEL + ks * 32 + lg * 8];

    f32x4 accz[4];
#pragma unroll
    for (int nd = 0; nd < 4; ++nd) accz[nd] = (f32x4){0.f, 0.f, 0.f, 0.f};
    float mq = -3.0e38f, Lq = 0.0f;

    for (int jc = 0; jc <= qblk * 64; jc += 64) {
      // ---- QK^T swapped: accs[n] = K_tile_n . Q^T ; row=key(4lg+r), col=q(lr)
      f32x4 accs[4];
#pragma unroll
      for (int n = 0; n < 4; ++n) accs[n] = (f32x4){0.f, 0.f, 0.f, 0.f};
#pragma unroll
      for (int ks = 0; ks < 2; ++ks) {
#pragma unroll
        for (int n = 0; n < 4; ++n) {
          const bf16x8v bk = *(const bf16x8v*)
              &Kb[qk_base + (size_t)(jc + n * 16 + lr) * DMODEL + ks * 32 + lg * 8];
          accs[n] = __builtin_amdgcn_mfma_f32_16x16x32_bf16(bk, bq[ks], accs[n], 0, 0, 0);
        }
      }
      // ---- mask + scale; lane-local max over its 16 keys
      float mx = -3.0e38f;
#pragma unroll
      for (int n = 0; n < 4; ++n) {
#pragma unroll
        for (int r = 0; r < 4; ++r) {
          float s = accs[n][r] * 0.125f;                       // 1/sqrt(64)
          s = (jc + n * 16 + 4 * lg + r <= myq) ? s : -3.0e38f;  // causal
          accs[n][r] = s;
          mx = fmaxf(mx, s);
        }
      }
      mx = fmaxf(mx, __shfl_xor(mx, 16, 64));
      mx = fmaxf(mx, __shfl_xor(mx, 32, 64));
      const float mn = fmaxf(mq, mx);
      const float c0 = __expf(mq - mn);
      // ---- exp, write P^T to LDS [q][key], lane-local partial sum
      float sum = 0.0f;
#pragma unroll
      for (int n = 0; n < 4; ++n) {
#pragma unroll
        for (int r = 0; r < 4; ++r) {
          const float pp = __expf(accs[n][r] - mn);
          sum += pp;
          Ps[w][lr][n * 16 + 4 * lg + r] = f2bf(pp);
        }
      }
      sum += __shfl_xor(sum, 16, 64);
      sum += __shfl_xor(sum, 32, 64);
      Lq = Lq * c0 + sum;
      mq = mn;
#pragma unroll
      for (int nd = 0; nd < 4; ++nd) accz[nd] *= c0;
      // ---- P A-side read (same-wave DS ordering): row=q(lr), k=keys
      bf16x8v ap[2];
#pragma unroll
      for (int ks = 0; ks < 2; ++ks)
        ap[ks] = *(const bf16x8v*)&Ps[w][lr][ks * 32 + lg * 8];
      // ---- PV swapped: accz[nd] = V^T_tile . P ; row=d(4lg+r), col=q(lr)
#pragma unroll
      for (int ks = 0; ks < 2; ++ks) {
#pragma unroll
        for (int nd = 0; nd < 4; ++nd) {
          const bf16x8v bv = *(const bf16x8v*)
              &Vt[vt_base + (size_t)(nd * 16 + lr) * ROWS + jc + ks * 32 + lg * 8];
          accz[nd] = __builtin_amdgcn_mfma_f32_16x16x32_bf16(bv, ap[ks], accz[nd], 0, 0, 0);
        }
      }
    }
    // ---- epilogue: lane's query row, d = nd*16 + 4lg + (0..3) contiguous
    const float rL = 1.0f / Lq;
    unsigned short* zrow = Zb + (size_t)((size_t)b * SEQ + myq) * DMODEL + h * DHEAD;
#pragma unroll
    for (int nd = 0; nd < 4; ++nd) {
      ushort4 o;
      o.x = f2bf(accz[nd][0] * rL);
      o.y = f2bf(accz[nd][1] * rL);
      o.z = f2bf(accz[nd][2] * rL);
      o.w = f2bf(accz[nd][3] * rL);
      *(ushort4*)(zrow + nd * 16 + 4 * lg) = o;
    }
  }
}

// ---------------------------------------------------------------- launch
extern "C" void kernel_launch(void* const* d_in, const int* in_sizes, int n_in,
                              void* d_out, int out_size, void* d_ws, size_t ws_size,
                              hipStream_t stream) {
  const float* resid_pre = (const float*)d_in[0];
  const float* ln1_w = (const float*)d_in[1];
  const float* ln1_b = (const float*)d_in[2];
  const float* W_Q = (const float*)d_in[3];
  const float* W_K = (const float*)d_in[4];
  const float* W_V = (const float*)d_in[5];
  const float* W_O = (const float*)d_in[6];
  const float* b_Q = (const float*)d_in[7];
  const float* b_K = (const float*)d_in[8];
  const float* b_V = (const float*)d_in[9];
  const float* b_O = (const float*)d_in[10];
  const float* ln2_w = (const float*)d_in[11];
  const float* ln2_b = (const float*)d_in[12];
  const float* W_in = (const float*)d_in[13];
  const float* b_in = (const float*)d_in[14];
  const float* W_out = (const float*)d_in[15];
  const float* b_out = (const float*)d_in[16];
  (void)in_sizes; (void)n_in; (void)out_size; (void)ws_size;

  float* out = (float*)d_out;
  char* w8 = (char*)d_ws;
  // Workspace map (56 MB used):
  //  [0,8M)    xln_b (LN1 out / LN2 out) ; Zb aliases (dead-time disjoint)
  //  [8,14M)   WQt/WKt/WVt  bf16 [1024,1024] x3 (B^T layout)
  //  [14,16M)  WOt   bf16 [1024,1024]
  //  [16,24M)  Wint  bf16 [4096,1024]
  //  [24,32M)  Woutt bf16 [1024,4096]
  //  [32,40M)  Qb bf16 [4096,1024]   \
  //  [40,48M)  Kb bf16 [4096,1024]    } dead after attn; hid_b [32,64M) reuses
  //  [48,56M)  Vt bf16 [1024,4096]   /
  unsigned short* xln_b = (unsigned short*)(w8);
  unsigned short* Zb    = (unsigned short*)(w8);
  unsigned short* WQt   = (unsigned short*)(w8 + (8u << 20));
  unsigned short* WOt   = (unsigned short*)(w8 + (14u << 20));
  unsigned short* Wint  = (unsigned short*)(w8 + (16u << 20));
  unsigned short* Woutt = (unsigned short*)(w8 + (24u << 20));
  unsigned short* Qb    = (unsigned short*)(w8 + (32u << 20));
  unsigned short* Kb    = (unsigned short*)(w8 + (40u << 20));
  unsigned short* Vt    = (unsigned short*)(w8 + (48u << 20));
  unsigned short* hid_b = (unsigned short*)(w8 + (32u << 20));

  // weight conversions (run every call; d_ws is re-poisoned)
  cvt_wqkv<<<dim3(16, 16, 3), 256, 0, stream>>>(W_Q, W_K, W_V, WQt);
  transpose_cvt<<<dim3(16, 16), 256, 0, stream>>>(W_O, WOt, DMODEL, DMODEL);
  transpose_cvt<<<dim3(64, 16), 256, 0, stream>>>(W_in, Wint, DMLP, DMODEL);
  transpose_cvt<<<dim3(16, 64), 256, 0, stream>>>(W_out, Woutt, DMODEL, DMLP);

  // LN1 -> bf16
  ln_bf16_kernel<<<ROWS, 256, 0, stream>>>(resid_pre, ln1_w, ln1_b, xln_b);
  // QKV projections -> bf16 (V directly transposed into Vt)
  dim3 g1024(ROWS / 128, 1024 / 128);
  gemm_bf16<5><<<g1024, 256, 0, stream>>>(xln_b, WQt, b_Q, nullptr, Qb, DMODEL, DMODEL);
  gemm_bf16<5><<<g1024, 256, 0, stream>>>(xln_b, WQt + (1u << 20), b_K, nullptr, Kb, DMODEL, DMODEL);
  gemm_bf16<4><<<g1024, 256, 0, stream>>>(xln_b, WQt + (2u << 20), b_V, nullptr, Vt, ROWS, DMODEL);
  // causal MFMA attention -> Zb (aliases xln_b; LN1 output is dead now)
  attn_mfma_kernel<<<512, 256, 0, stream>>>(Qb, Kb, Vt, Zb);
  // W_O projection + bias + residual -> d_out = resid_mid
  gemm_bf16<2><<<g1024, 256, 0, stream>>>(Zb, WOt, b_O, resid_pre, out, DMODEL, DMODEL);
  // LN2 -> bf16 (overwrites Zb region after W_O consumed it)
  ln_bf16_kernel<<<ROWS, 256, 0, stream>>>(out, ln2_w, ln2_b, xln_b);
  // MLP in + GELU -> bf16 hid
  dim3 gin(ROWS / 128, DMLP / 128);
  gemm_bf16<1><<<gin, 256, 0, stream>>>(xln_b, Wint, b_in, nullptr, hid_b, DMLP, DMODEL);
  // MLP out, accumulate into resid_mid in d_out
  gemm_bf16<3><<<g1024, 256, 0, stream>>>(hid_b, Woutt, b_out, nullptr, out, DMODEL, DMLP);
}

// Round 6
// 502.488 us; speedup vs baseline: 5.0341x; 1.1023x over previous
//
#include <hip/hip_runtime.h>
#include <cstdint>
#include <cstddef>

// Problem constants (B=2, S=2048, D=1024, H=16, DH=64, DM=4096)
#define SEQ    2048
#define DMODEL 1024
#define NHEAD  16
#define DHEAD  64
#define DMLP   4096
#define ROWS   4096   // B*S

typedef __attribute__((ext_vector_type(8))) short bf16x8v;  // 8 bf16 (4 VGPRs)
typedef __attribute__((ext_vector_type(4))) float f32x4;

// ---------------------------------------------------------------- utilities
__device__ __forceinline__ float wave_reduce_sum(float v) {
#pragma unroll
  for (int off = 32; off; off >>= 1) v += __shfl_xor(v, off, 64);
  return v;
}
__device__ __forceinline__ float gelu_new(float x) {
  // 0.5*x*(1+tanh(sqrt(2/pi)*(x+0.044715*x^3)))  (jax.nn.gelu approximate=True)
  const float c = 0.7978845608028654f;
  float inner = c * (x + 0.044715f * x * x * x);
  return 0.5f * x * (1.0f + tanhf(inner));
}
__device__ __forceinline__ unsigned short f2bf(float x) {  // RNE f32->bf16
  union { float f; unsigned u; } v; v.f = x;
  unsigned r = v.u + 0x7fffu + ((v.u >> 16) & 1u);
  return (unsigned short)(r >> 16);
}
// async global->LDS, 16B per lane (global addr per-lane; LDS base wave-uniform)
__device__ __forceinline__ void gload_lds16(const void* g, void* l) {
  __builtin_amdgcn_global_load_lds(
      (const __attribute__((address_space(1))) unsigned int*)g,
      (__attribute__((address_space(3))) unsigned int*)l, 16, 0, 0);
}

// ---------------------------------------------------------------- LayerNorm
// TransformerLens LN -> bf16 output (feeds MFMA GEMMs).
__global__ __launch_bounds__(256)
void ln_bf16_kernel(const float* __restrict__ x, const float* __restrict__ w,
                    const float* __restrict__ b, unsigned short* __restrict__ y) {
  __shared__ float sred[4];
  const int r = blockIdx.x;
  const int t = threadIdx.x;
  const int wid = t >> 6, lane = t & 63;
  const float4 v = ((const float4*)(x + (size_t)r * DMODEL))[t];

  float s = v.x + v.y + v.z + v.w;
  s = wave_reduce_sum(s);
  if (lane == 0) sred[wid] = s;
  __syncthreads();
  const float mean = (sred[0] + sred[1] + sred[2] + sred[3]) * (1.0f / DMODEL);
  __syncthreads();

  float4 c;
  c.x = v.x - mean; c.y = v.y - mean; c.z = v.z - mean; c.w = v.w - mean;
  float ss = c.x * c.x + c.y * c.y + c.z * c.z + c.w * c.w;
  ss = wave_reduce_sum(ss);
  if (lane == 0) sred[wid] = ss;
  __syncthreads();
  const float rs =
      rsqrtf((sred[0] + sred[1] + sred[2] + sred[3]) * (1.0f / DMODEL) + 1e-5f);

  const float4 wv = ((const float4*)w)[t];
  const float4 bv = ((const float4*)b)[t];
  ushort4 o;
  o.x = f2bf(c.x * rs * wv.x + bv.x);
  o.y = f2bf(c.y * rs * wv.y + bv.y);
  o.z = f2bf(c.z * rs * wv.z + bv.z);
  o.w = f2bf(c.w * rs * wv.w + bv.w);
  ((ushort4*)(y + (size_t)r * DMODEL))[t] = o;
}

// ------------------------------------------------- weight convert/transpose
// Generic 64x64-tile transpose + f32->bf16: dst[c][r] = src[r][c].
__global__ __launch_bounds__(256)
void transpose_cvt(const float* __restrict__ src, unsigned short* __restrict__ dst,
                   int ld_src, int ld_dst) {
  __shared__ float t[64][68];
  const int r0 = blockIdx.y * 64, c0 = blockIdx.x * 64;
  const int tid = threadIdx.x;
  const int c4 = (tid & 15) * 4, r = tid >> 4;
#pragma unroll
  for (int p = 0; p < 4; ++p) {
    const float4 v = *(const float4*)(src + (size_t)(r0 + r + p * 16) * ld_src + c0 + c4);
    *(float4*)&t[r + p * 16][c4] = v;
  }
  __syncthreads();
  const int r4 = (tid & 15) * 4, c = tid >> 4;
#pragma unroll
  for (int p = 0; p < 4; ++p) {
    const int cc = c + p * 16;
    ushort4 o;
    o.x = f2bf(t[r4 + 0][cc]);
    o.y = f2bf(t[r4 + 1][cc]);
    o.z = f2bf(t[r4 + 2][cc]);
    o.w = f2bf(t[r4 + 3][cc]);
    *(ushort4*)(dst + (size_t)(c0 + cc) * ld_dst + r0 + r4) = o;
  }
}

// W_{Q,K,V}[H, D, DH] f32 -> Bt[h*64+dh][d] bf16 (3 weights, contiguous out).
__global__ __launch_bounds__(256)
void cvt_wqkv(const float* __restrict__ Wq, const float* __restrict__ Wk,
              const float* __restrict__ Wv, unsigned short* __restrict__ out) {
  __shared__ float t[64][68];
  const float* src = (blockIdx.z == 0) ? Wq : (blockIdx.z == 1) ? Wk : Wv;
  unsigned short* dst = out + (size_t)blockIdx.z * (DMODEL * NHEAD * DHEAD);
  const int h = blockIdx.y, d0 = blockIdx.x * 64;
  const int tid = threadIdx.x;
  const int c4 = (tid & 15) * 4, r = tid >> 4;
#pragma unroll
  for (int p = 0; p < 4; ++p) {
    const float4 v = *(const float4*)(src + (size_t)h * (DMODEL * DHEAD) +
                                      (size_t)(d0 + r + p * 16) * DHEAD + c4);
    *(float4*)&t[r + p * 16][c4] = v;
  }
  __syncthreads();
  const int r4 = (tid & 15) * 4, c = tid >> 4;
#pragma unroll
  for (int p = 0; p < 4; ++p) {
    const int cc = c + p * 16;  // dh index
    ushort4 o;
    o.x = f2bf(t[r4 + 0][cc]);
    o.y = f2bf(t[r4 + 1][cc]);
    o.z = f2bf(t[r4 + 2][cc]);
    o.w = f2bf(t[r4 + 3][cc]);
    *(ushort4*)(dst + (size_t)(h * 64 + cc) * DMODEL + d0 + r4) = o;
  }
}

// ---------------------------------------------------------------- MFMA GEMM
// C[M x N] = A[M x K](bf16,row-major) @ Bt[N x K](bf16,row-major)^T + bias.
// m97 structure: 128x128 tile, BK=32, 4 waves, global_load_lds w16, 2 barriers.
// EPI: 0 = f32 store; 1 = bf16 gelu store; 2 = f32 + addend; 3 = f32 accum;
//      4 = bf16 TRANSPOSED store (Cout[col][ldc] layout, packed ushort4);
//      5 = bf16 store.
template <int EPI>
__global__ __launch_bounds__(256)
void gemm_bf16(const unsigned short* __restrict__ A,
               const unsigned short* __restrict__ Bt,
               const float* __restrict__ bias, const float* __restrict__ addend,
               void* __restrict__ Cout, int ldc, int K) {
  __shared__ unsigned short As[128 * 32];  // [row][k] linear, rows of 64B
  __shared__ unsigned short Bs[128 * 32];
  const int tid = threadIdx.x;
  const int w = tid >> 6, lane = tid & 63;
  const int wr = w >> 1, wc = w & 1;           // wave -> 64x64 quadrant
  const int m0 = blockIdx.x * 128, n0 = blockIdx.y * 128;

  f32x4 acc[4][4];
#pragma unroll
  for (int m = 0; m < 4; ++m)
#pragma unroll
    for (int n = 0; n < 4; ++n) acc[m][n] = (f32x4){0.f, 0.f, 0.f, 0.f};

  const int srow = w * 32 + (lane >> 2);       // staging row within tile
  const int scol = (lane & 3) * 8;             // staging k-offset (8 bf16 = 16B)

  for (int k0 = 0; k0 < K; k0 += 32) {
    __syncthreads();  // all waves done reading previous tile
#pragma unroll
    for (int it = 0; it < 2; ++it) {
      const int row = srow + it * 16;
      gload_lds16(A + (size_t)(m0 + row) * K + k0 + scol,
                  &As[(w * 32 + it * 16) * 32]);
      gload_lds16(Bt + (size_t)(n0 + row) * K + k0 + scol,
                  &Bs[(w * 32 + it * 16) * 32]);
    }
    __syncthreads();  // staging complete (vmcnt drained at barrier)

    bf16x8v af[4], bf[4];
#pragma unroll
    for (int m = 0; m < 4; ++m)
      af[m] = *(const bf16x8v*)&As[(wr * 64 + m * 16 + (lane & 15)) * 32 + (lane >> 4) * 8];
#pragma unroll
    for (int n = 0; n < 4; ++n)
      bf[n] = *(const bf16x8v*)&Bs[(wc * 64 + n * 16 + (lane & 15)) * 32 + (lane >> 4) * 8];
#pragma unroll
    for (int m = 0; m < 4; ++m)
#pragma unroll
      for (int n = 0; n < 4; ++n)
        acc[m][n] = __builtin_amdgcn_mfma_f32_16x16x32_bf16(af[m], bf[n], acc[m][n], 0, 0, 0);
  }

  // epilogue: C/D layout col = lane&15, row = (lane>>4)*4 + reg  [m89]
#pragma unroll
  for (int m = 0; m < 4; ++m) {
    const int row = m0 + wr * 64 + m * 16 + (lane >> 4) * 4;
#pragma unroll
    for (int n = 0; n < 4; ++n) {
      const int col = n0 + wc * 64 + n * 16 + (lane & 15);
      const float bcol = bias[col];
      const f32x4 a = acc[m][n];
      if (EPI == 4) {
        // transposed bf16 store: 4 contiguous rows in dst row `col`
        ushort4 o;
        o.x = f2bf(a[0] + bcol); o.y = f2bf(a[1] + bcol);
        o.z = f2bf(a[2] + bcol); o.w = f2bf(a[3] + bcol);
        *(ushort4*)((unsigned short*)Cout + (size_t)col * ldc + row) = o;
      } else {
#pragma unroll
        for (int r = 0; r < 4; ++r) {
          const float val = a[r] + bcol;
          const size_t off = (size_t)(row + r) * ldc + col;
          if (EPI == 0) {
            ((float*)Cout)[off] = val;
          } else if (EPI == 1) {
            ((unsigned short*)Cout)[off] = f2bf(gelu_new(val));
          } else if (EPI == 2) {
            ((float*)Cout)[off] = val + addend[off];
          } else if (EPI == 3) {
            ((float*)Cout)[off] += val;
          } else {  // EPI == 5
            ((unsigned short*)Cout)[off] = f2bf(val);
          }
        }
      }
    }
  }
}

// ------------------------------------------- fused QKV GEMM (N = 3072)
// C[4096 x 3072] = xln @ (WQt||WKt||WVt)^T; per-block epilogue switch:
// blockIdx.y>>3 = 0 -> Qb (bf16), 1 -> Kb (bf16), 2 -> Vt (bf16 transposed).
__global__ __launch_bounds__(256)
void gemm_qkv(const unsigned short* __restrict__ A,
              const unsigned short* __restrict__ Bt,  // [3072][1024]
              const float* __restrict__ bQ, const float* __restrict__ bK,
              const float* __restrict__ bV,
              unsigned short* __restrict__ Qb, unsigned short* __restrict__ Kb,
              unsigned short* __restrict__ Vt) {
  __shared__ unsigned short As[128 * 32];
  __shared__ unsigned short Bs[128 * 32];
  const int tid = threadIdx.x;
  const int w = tid >> 6, lane = tid & 63;
  const int wr = w >> 1, wc = w & 1;
  const int m0 = blockIdx.x * 128, n0 = blockIdx.y * 128;

  f32x4 acc[4][4];
#pragma unroll
  for (int m = 0; m < 4; ++m)
#pragma unroll
    for (int n = 0; n < 4; ++n) acc[m][n] = (f32x4){0.f, 0.f, 0.f, 0.f};

  const int srow = w * 32 + (lane >> 2);
  const int scol = (lane & 3) * 8;

  for (int k0 = 0; k0 < DMODEL; k0 += 32) {
    __syncthreads();
#pragma unroll
    for (int it = 0; it < 2; ++it) {
      const int row = srow + it * 16;
      gload_lds16(A + (size_t)(m0 + row) * DMODEL + k0 + scol,
                  &As[(w * 32 + it * 16) * 32]);
      gload_lds16(Bt + (size_t)(n0 + row) * DMODEL + k0 + scol,
                  &Bs[(w * 32 + it * 16) * 32]);
    }
    __syncthreads();

    bf16x8v af[4], bf[4];
#pragma unroll
    for (int m = 0; m < 4; ++m)
      af[m] = *(const bf16x8v*)&As[(wr * 64 + m * 16 + (lane & 15)) * 32 + (lane >> 4) * 8];
#pragma unroll
    for (int n = 0; n < 4; ++n)
      bf[n] = *(const bf16x8v*)&Bs[(wc * 64 + n * 16 + (lane & 15)) * 32 + (lane >> 4) * 8];
#pragma unroll
    for (int m = 0; m < 4; ++m)
#pragma unroll
      for (int n = 0; n < 4; ++n)
        acc[m][n] = __builtin_amdgcn_mfma_f32_16x16x32_bf16(af[m], bf[n], acc[m][n], 0, 0, 0);
  }

  const int which = blockIdx.y >> 3;  // uniform per block: 0=Q, 1=K, 2=V
  const float* bias = (which == 0) ? bQ : (which == 1) ? bK : bV;
#pragma unroll
  for (int m = 0; m < 4; ++m) {
    const int row = m0 + wr * 64 + m * 16 + (lane >> 4) * 4;
#pragma unroll
    for (int n = 0; n < 4; ++n) {
      const int col = (n0 + wc * 64 + n * 16 + (lane & 15)) & 1023;  // within matrix
      const float bcol = bias[col];
      const f32x4 a = acc[m][n];
      if (which == 2) {  // V: transposed store Vt[col][row]
        ushort4 o;
        o.x = f2bf(a[0] + bcol); o.y = f2bf(a[1] + bcol);
        o.z = f2bf(a[2] + bcol); o.w = f2bf(a[3] + bcol);
        *(ushort4*)(Vt + (size_t)col * ROWS + row) = o;
      } else {
        unsigned short* dst = which ? Kb : Qb;
#pragma unroll
        for (int r = 0; r < 4; ++r)
          dst[(size_t)(row + r) * DMODEL + col] = f2bf(a[r] + bcol);
      }
    }
  }
}

// ---------------------------------------------------------------- Attention
// Causal MFMA flash attention, bf16 inputs, fp32 accum, swapped-operand form
// (S^T: col=q, row=key -> lane-local softmax stats, 2 shfl_xor per reduce).
// XCD locality: bid = pr*32 + bh so bid%8 == bh%8 -> all 16 blocks of one
// (b,h) land on one XCD; its 512 KB K+V slab stays in that XCD's L2.
// Pipeline: K-fragments for chunk jc+64 prefetched into registers during
// chunk jc; V loads issued before softmax (drain under the VALU work).
// Mask applied only on the diagonal chunk (uniform branch).
// Load balance: block pr handles qblk=pr then 31-pr (33 chunks uniform).
__global__ __launch_bounds__(256)
void attn_mfma_kernel(const unsigned short* __restrict__ Qb,
                      const unsigned short* __restrict__ Kb,
                      const unsigned short* __restrict__ Vt,
                      unsigned short* __restrict__ Zb) {
  __shared__ unsigned short Ps[4][16][72];  // per-wave P: [qloc][key], padded
  const int tid = threadIdx.x;
  const int w = tid >> 6, lane = tid & 63;
  const int lg = lane >> 4, lr = lane & 15;
  const int bh = blockIdx.x & 31;          // b*16 + h  (bid%8 == bh%8)
  const int pr = blockIdx.x >> 5;          // pair index 0..15
  const int h = bh & 15, b = bh >> 4;
  const size_t qk_base = (size_t)b * SEQ * DMODEL + (size_t)h * DHEAD;
  const size_t vt_base = (size_t)(h * DHEAD) * ROWS + (size_t)b * SEQ;

  for (int sel = 0; sel < 2; ++sel) {
    const int qblk = sel ? (31 - pr) : pr;
    const int q0 = qblk * 64 + w * 16;     // wave's first query
    const int myq = q0 + lr;               // this lane's query (col index)
    const int jlast = qblk * 64;           // last (diagonal) chunk start

    // Q B-fragment: col=lr -> query myq, k(dim) = ks*32 + lg*8 + 0..7
    bf16x8v bq[2];
#pragma unroll
    for (int ks = 0; ks < 2; ++ks)
      bq[ks] = *(const bf16x8v*)&Qb[qk_base + (size_t)myq * DMODEL + ks * 32 + lg * 8];

    f32x4 accz[4];
#pragma unroll
    for (int nd = 0; nd < 4; ++nd) accz[nd] = (f32x4){0.f, 0.f, 0.f, 0.f};
    float mq = -3.0e38f, Lq = 0.0f;

    // prefetch K fragments for first chunk
    bf16x8v kf[2][4];
#pragma unroll
    for (int ks = 0; ks < 2; ++ks)
#pragma unroll
      for (int n = 0; n < 4; ++n)
        kf[ks][n] = *(const bf16x8v*)
            &Kb[qk_base + (size_t)(n * 16 + lr) * DMODEL + ks * 32 + lg * 8];

    for (int jc = 0; jc <= jlast; jc += 64) {
      // ---- QK^T swapped: accs[n] = K_tile_n . Q^T ; row=key(4lg+r), col=q(lr)
      f32x4 accs[4];
#pragma unroll
      for (int n = 0; n < 4; ++n) accs[n] = (f32x4){0.f, 0.f, 0.f, 0.f};
#pragma unroll
      for (int ks = 0; ks < 2; ++ks)
#pragma unroll
        for (int n = 0; n < 4; ++n)
          accs[n] = __builtin_amdgcn_mfma_f32_16x16x32_bf16(kf[ks][n], bq[ks], accs[n], 0, 0, 0);

      // ---- prefetch next chunk's K fragments (hidden under softmax+PV)
      const int jn = jc + 64;
      if (jn <= jlast) {
#pragma unroll
        for (int ks = 0; ks < 2; ++ks)
#pragma unroll
          for (int n = 0; n < 4; ++n)
            kf[ks][n] = *(const bf16x8v*)
                &Kb[qk_base + (size_t)(jn + n * 16 + lr) * DMODEL + ks * 32 + lg * 8];
      }
      // ---- V fragments issued early (independent of softmax)
      bf16x8v vf[2][4];
#pragma unroll
      for (int ks = 0; ks < 2; ++ks)
#pragma unroll
        for (int nd = 0; nd < 4; ++nd)
          vf[ks][nd] = *(const bf16x8v*)
              &Vt[vt_base + (size_t)(nd * 16 + lr) * ROWS + jc + ks * 32 + lg * 8];

      // ---- scale (+ mask only on diagonal chunk); lane-local max
      float mx = -3.0e38f;
      if (jc == jlast) {
#pragma unroll
        for (int n = 0; n < 4; ++n)
#pragma unroll
          for (int r = 0; r < 4; ++r) {
            float s = accs[n][r] * 0.125f;                        // 1/sqrt(64)
            s = (jc + n * 16 + 4 * lg + r <= myq) ? s : -3.0e38f;  // causal
            accs[n][r] = s; mx = fmaxf(mx, s);
          }
      } else {
#pragma unroll
        for (int n = 0; n < 4; ++n)
#pragma unroll
          for (int r = 0; r < 4; ++r) {
            const float s = accs[n][r] * 0.125f;
            accs[n][r] = s; mx = fmaxf(mx, s);
          }
      }
      mx = fmaxf(mx, __shfl_xor(mx, 16, 64));
      mx = fmaxf(mx, __shfl_xor(mx, 32, 64));
      const float mn = fmaxf(mq, mx);
      const float c0 = __expf(mq - mn);
      // ---- exp, packed P^T writes to LDS [q][key], lane-local partial sum
      float sum = 0.0f;
#pragma unroll
      for (int n = 0; n < 4; ++n) {
        ushort4 pk;
        float e0 = __expf(accs[n][0] - mn), e1 = __expf(accs[n][1] - mn);
        float e2 = __expf(accs[n][2] - mn), e3 = __expf(accs[n][3] - mn);
        sum += e0 + e1 + e2 + e3;
        pk.x = f2bf(e0); pk.y = f2bf(e1); pk.z = f2bf(e2); pk.w = f2bf(e3);
        *(ushort4*)&Ps[w][lr][n * 16 + 4 * lg] = pk;
      }
      sum += __shfl_xor(sum, 16, 64);
      sum += __shfl_xor(sum, 32, 64);
      Lq = Lq * c0 + sum;
      mq = mn;
#pragma unroll
      for (int nd = 0; nd < 4; ++nd) accz[nd] *= c0;
      // ---- P A-side read (same-wave DS ordering): row=q(lr), k=keys
      bf16x8v ap[2];
#pragma unroll
      for (int ks = 0; ks < 2; ++ks)
        ap[ks] = *(const bf16x8v*)&Ps[w][lr][ks * 32 + lg * 8];
      // ---- PV swapped: accz[nd] = V^T_tile . P ; row=d(4lg+r), col=q(lr)
#pragma unroll
      for (int ks = 0; ks < 2; ++ks)
#pragma unroll
        for (int nd = 0; nd < 4; ++nd)
          accz[nd] = __builtin_amdgcn_mfma_f32_16x16x32_bf16(vf[ks][nd], ap[ks], accz[nd], 0, 0, 0);
    }
    // ---- epilogue: lane's query row, d = nd*16 + 4lg + (0..3) contiguous
    const float rL = 1.0f / Lq;
    unsigned short* zrow = Zb + (size_t)((size_t)b * SEQ + myq) * DMODEL + h * DHEAD;
#pragma unroll
    for (int nd = 0; nd < 4; ++nd) {
      ushort4 o;
      o.x = f2bf(accz[nd][0] * rL);
      o.y = f2bf(accz[nd][1] * rL);
      o.z = f2bf(accz[nd][2] * rL);
      o.w = f2bf(accz[nd][3] * rL);
      *(ushort4*)(zrow + nd * 16 + 4 * lg) = o;
    }
  }
}

// ---------------------------------------------------------------- launch
extern "C" void kernel_launch(void* const* d_in, const int* in_sizes, int n_in,
                              void* d_out, int out_size, void* d_ws, size_t ws_size,
                              hipStream_t stream) {
  const float* resid_pre = (const float*)d_in[0];
  const float* ln1_w = (const float*)d_in[1];
  const float* ln1_b = (const float*)d_in[2];
  const float* W_Q = (const float*)d_in[3];
  const float* W_K = (const float*)d_in[4];
  const float* W_V = (const float*)d_in[5];
  const float* W_O = (const float*)d_in[6];
  const float* b_Q = (const float*)d_in[7];
  const float* b_K = (const float*)d_in[8];
  const float* b_V = (const float*)d_in[9];
  const float* b_O = (const float*)d_in[10];
  const float* ln2_w = (const float*)d_in[11];
  const float* ln2_b = (const float*)d_in[12];
  const float* W_in = (const float*)d_in[13];
  const float* b_in = (const float*)d_in[14];
  const float* W_out = (const float*)d_in[15];
  const float* b_out = (const float*)d_in[16];
  (void)in_sizes; (void)n_in; (void)out_size; (void)ws_size;

  float* out = (float*)d_out;
  char* w8 = (char*)d_ws;
  // Workspace map (56 MB used):
  //  [0,8M)    xln_b (LN1 out / LN2 out) ; Zb aliases (dead-time disjoint)
  //  [8,14M)   WQt/WKt/WVt  bf16 [3072,1024] contiguous (B^T layout)
  //  [14,16M)  WOt   bf16 [1024,1024]
  //  [16,24M)  Wint  bf16 [4096,1024]
  //  [24,32M)  Woutt bf16 [1024,4096]
  //  [32,40M)  Qb bf16 [4096,1024]   \
  //  [40,48M)  Kb bf16 [4096,1024]    } dead after attn; hid_b [32,64M) reuses
  //  [48,56M)  Vt bf16 [1024,4096]   /
  unsigned short* xln_b = (unsigned short*)(w8);
  unsigned short* Zb    = (unsigned short*)(w8);
  unsigned short* WQt   = (unsigned short*)(w8 + (8u << 20));
  unsigned short* WOt   = (unsigned short*)(w8 + (14u << 20));
  unsigned short* Wint  = (unsigned short*)(w8 + (16u << 20));
  unsigned short* Woutt = (unsigned short*)(w8 + (24u << 20));
  unsigned short* Qb    = (unsigned short*)(w8 + (32u << 20));
  unsigned short* Kb    = (unsigned short*)(w8 + (40u << 20));
  unsigned short* Vt    = (unsigned short*)(w8 + (48u << 20));
  unsigned short* hid_b = (unsigned short*)(w8 + (32u << 20));

  // weight conversions (run every call; d_ws is re-poisoned)
  cvt_wqkv<<<dim3(16, 16, 3), 256, 0, stream>>>(W_Q, W_K, W_V, WQt);
  transpose_cvt<<<dim3(16, 16), 256, 0, stream>>>(W_O, WOt, DMODEL, DMODEL);
  transpose_cvt<<<dim3(64, 16), 256, 0, stream>>>(W_in, Wint, DMLP, DMODEL);
  transpose_cvt<<<dim3(16, 64), 256, 0, stream>>>(W_out, Woutt, DMODEL, DMLP);

  // LN1 -> bf16
  ln_bf16_kernel<<<ROWS, 256, 0, stream>>>(resid_pre, ln1_w, ln1_b, xln_b);
  // fused QKV projection -> Qb, Kb, Vt(transposed)
  gemm_qkv<<<dim3(32, 24), 256, 0, stream>>>(xln_b, WQt, b_Q, b_K, b_V, Qb, Kb, Vt);
  // causal MFMA attention -> Zb (aliases xln_b; LN1 output is dead now)
  attn_mfma_kernel<<<512, 256, 0, stream>>>(Qb, Kb, Vt, Zb);
  // W_O projection + bias + residual -> d_out = resid_mid
  dim3 g1024(ROWS / 128, 1024 / 128);
  gemm_bf16<2><<<g1024, 256, 0, stream>>>(Zb, WOt, b_O, resid_pre, out, DMODEL, DMODEL);
  // LN2 -> bf16 (overwrites Zb region after W_O consumed it)
  ln_bf16_kernel<<<ROWS, 256, 0, stream>>>(out, ln2_w, ln2_b, xln_b);
  // MLP in + GELU -> bf16 hid
  dim3 gin(ROWS / 128, DMLP / 128);
  gemm_bf16<1><<<gin, 256, 0, stream>>>(xln_b, Wint, b_in, nullptr, hid_b, DMLP, DMODEL);
  // MLP out, accumulate into resid_mid in d_out
  gemm_bf16<3><<<g1024, 256, 0, stream>>>(hid_b, Woutt, b_out, nullptr, out, DMODEL, DMLP);
}